// Round 10
// baseline (1304.077 us; speedup 1.0000x reference)
//
#include <hip/hip_runtime.h>
#include <hip/hip_bf16.h>

#define B_ 8
#define L_ 1024
#define BL (B_*L_)
#define DENC 128
#define DMAIN 256
#define VOCAB 260
#define NHEADS 4

typedef __hip_bfloat16 bf16;
typedef _Float16 f16;
typedef f16 half8 __attribute__((ext_vector_type(8)));
typedef f16 half4 __attribute__((ext_vector_type(4)));
typedef f16 half2v __attribute__((ext_vector_type(2)));
typedef float f32x4 __attribute__((ext_vector_type(4)));

// ---------------- dtype detector ----------------
__global__ __launch_bounds__(64) void k_detect(const void* __restrict__ emb, int* __restrict__ flag){
    int lane = threadIdx.x;
    const unsigned short* u = (const unsigned short*)emb;
    int bad = 0;
    #pragma unroll
    for (int j = 0; j < 4; j++){
        unsigned short h = u[lane + 64*j];
        bf16 t = *(const bf16*)&h;
        float v = __bfloat162float(t);
        if (!(fabsf(v) < 1e4f)) bad++;
    }
    #pragma unroll
    for (int o = 32; o >= 1; o >>= 1) bad += __shfl_xor(bad, o);
    if (lane == 0) flag[0] = (bad == 0) ? 1 : 0;
}

// ---------------- fused convert: f32 master + f16 copy ----------------
struct CvtArgs {
    const void* src[31];
    unsigned offs[32];
};
__global__ void k_cvt_all(CvtArgs a, float* __restrict__ dst, f16* __restrict__ dst16,
                          int total, const int* __restrict__ flag){
    int isbf = flag[0];
    for (int i = blockIdx.x*256 + threadIdx.x; i < total; i += gridDim.x*256){
        int lo = 0, hi = 30;
        while (lo < hi){ int mid = (lo+hi+1)>>1; if (a.offs[mid] <= (unsigned)i) lo = mid; else hi = mid-1; }
        int j = i - (int)a.offs[lo];
        float v = isbf ? __bfloat162float(((const bf16*)a.src[lo])[j])
                       : ((const float*)a.src[lo])[j];
        dst[i] = v;
        dst16[i] = (f16)v;
    }
}

// ---------------- embed gather ----------------
__global__ void k_embed(const int* __restrict__ ids, const float* __restrict__ emb, float* __restrict__ x){
    int i = blockIdx.x*256 + threadIdx.x;
    int row = i >> 7, d = i & 127;
    x[i] = emb[ids[row]*DENC + d];
}

// ---------------- layernorm: f32 in -> f16 out, 4 rows/block ----------------
template<int D>
__global__ __launch_bounds__(256) void k_ln16(const float* __restrict__ x, const float* __restrict__ w,
                                              const float* __restrict__ b, f16* __restrict__ y){
    int row = blockIdx.x*4 + (threadIdx.x >> 6);
    int lane = threadIdx.x & 63;
    const float* xr = x + (size_t)row*D;
    float v[D/64];
    float s = 0.f;
    #pragma unroll
    for (int j=0;j<D/64;j++){ v[j] = xr[lane + j*64]; s += v[j]; }
    #pragma unroll
    for (int o=32;o>=1;o>>=1) s += __shfl_xor(s,o);
    float mu = s / (float)D;
    float s2 = 0.f;
    #pragma unroll
    for (int j=0;j<D/64;j++){ float dd = v[j]-mu; s2 += dd*dd; }
    #pragma unroll
    for (int o=32;o>=1;o>>=1) s2 += __shfl_xor(s2,o);
    float inv = rsqrtf(s2/(float)D + 1e-5f);
    f16* yr = y + (size_t)row*D;
    #pragma unroll
    for (int j=0;j<D/64;j++){
        int d = lane + j*64;
        yr[d] = (f16)((v[j]-mu)*inv*w[d] + b[d]);
    }
}

// ---------------- f32 vector GEMM: fused wq/wk (router only) ----------------
#define GBM 64
#define GBN 64
#define GBK 32
__global__ __launch_bounds__(256) void k_gemm2(const float* __restrict__ A, const float* __restrict__ Wq,
        const float* __restrict__ Wk, float* __restrict__ Cq, float* __restrict__ Ck, int K)
{
    __shared__ float As[GBK][GBM+4];
    __shared__ float Ws[GBK][GBN+4];
    int tid = threadIdx.x;
    int bm = blockIdx.y * GBM;
    int bn = blockIdx.x * GBN;
    int tx = tid & 15, ty = tid >> 4;
    float acc[4][4] = {};
    for (int k0 = 0; k0 < K; k0 += GBK){
        #pragma unroll
        for (int i = tid; i < GBM*GBK; i += 256){
            int m = i >> 5, kk = i & 31;
            As[kk][m] = A[(size_t)(bm+m)*K + k0 + kk];
        }
        #pragma unroll
        for (int i = tid; i < GBN*GBK; i += 256){
            int n = i >> 5, kk = i & 31;
            int gn = bn + n;
            const float* W = (gn < 128) ? Wq : Wk;
            int wr = gn & 127;
            Ws[kk][n] = W[(size_t)wr*K + k0 + kk];
        }
        __syncthreads();
        #pragma unroll
        for (int kk = 0; kk < GBK; kk++){
            float a0[4], w0[4];
            *(float4*)a0 = *(const float4*)&As[kk][ty*4];
            *(float4*)w0 = *(const float4*)&Ws[kk][tx*4];
            #pragma unroll
            for (int i=0;i<4;i++)
                #pragma unroll
                for (int j=0;j<4;j++) acc[i][j] += a0[i]*w0[j];
        }
        __syncthreads();
    }
    #pragma unroll
    for (int i=0;i<4;i++){
        int m = bm + ty*4 + i;
        #pragma unroll
        for (int j=0;j<4;j++){
            int n = bn + tx*4 + j;
            float* C = (n < 128) ? Cq : Ck;
            C[(size_t)m*128 + (n & 127)] = acc[i][j];
        }
    }
}

// ---------------- f16 MFMA GEMM, BK=64, BM x 64 tile ----------------
// modes: 0 C f32, 1 C = R + A@W^T, 2 gelu->C16 f16, 3 out-store, 5 split-head QKV f16 (V^T)
// BM=64: 4 waves 2x2 (32x32 each). BM=128: 4 waves stacked on M (32 rows x 64 cols each).
template<int K, int BM>
__global__ __launch_bounds__(256) void k_hgemm(const f16* __restrict__ A, const f16* __restrict__ W,
        const float* __restrict__ R, float* __restrict__ C, f16* __restrict__ C16,
        void* __restrict__ OutRaw, const int* __restrict__ flag, int N, int mode,
        f16* __restrict__ Qd, f16* __restrict__ Kd, f16* __restrict__ Vd,
        int dShift, int dhShift)
{
    constexpr int NJ = (BM == 128) ? 4 : 2;
    __shared__ half8 As[BM*8];     // [row][8] of half8 (BK=64 halves)
    __shared__ half8 Ws[64*8];
    int tid = threadIdx.x;
    int wave = tid >> 6, lane = tid & 63;
    int quad = lane >> 4, l15 = lane & 15;
    int bm = blockIdx.y * BM, bn = blockIdx.x * 64;
    int mrow0 = (BM == 128) ? wave*32 : (wave>>1)*32;
    int ncol0 = (BM == 128) ? 0 : (wave&1)*32;

    f32x4 acc[2][NJ] = {};

    for (int k0 = 0; k0 < K; k0 += 64){
        __syncthreads();
        #pragma unroll
        for (int s = 0; s < BM/32; s++){
            int slot = s*256 + tid;
            int row = slot >> 3, col = slot & 7;
            As[slot] = *(const half8*)(A + (size_t)(bm+row)*K + k0 + col*8);
        }
        #pragma unroll
        for (int s = 0; s < 2; s++){
            int slot = s*256 + tid;
            int row = slot >> 3, col = slot & 7;
            int gn = bn + row;
            Ws[slot] = (gn < N) ? *(const half8*)(W + (size_t)gn*K + k0 + col*8) : (half8)(f16)0.f;
        }
        __syncthreads();
        #pragma unroll
        for (int ks = 0; ks < 2; ks++){
            half8 af[2], wf[NJ];
            #pragma unroll
            for (int i=0;i<2;i++) af[i] = As[(mrow0 + i*16 + l15)*8 + ks*4 + quad];
            #pragma unroll
            for (int j=0;j<NJ;j++) wf[j] = Ws[(ncol0 + j*16 + l15)*8 + ks*4 + quad];
            #pragma unroll
            for (int i=0;i<2;i++)
                #pragma unroll
                for (int j=0;j<NJ;j++)
                    acc[i][j] = __builtin_amdgcn_mfma_f32_16x16x32_f16(af[i], wf[j], acc[i][j], 0, 0, 0);
        }
    }

    #pragma unroll
    for (int j=0;j<NJ;j++){
        int n = bn + ncol0 + j*16 + l15;
        if (n >= N) continue;
        #pragma unroll
        for (int i=0;i<2;i++){
            #pragma unroll
            for (int r=0;r<4;r++){
                int m = bm + mrow0 + i*16 + quad*4 + r;
                float v = acc[i][j][r];
                if (mode == 5){
                    int which = n >> dShift;
                    int rem = n & ((1<<dShift)-1);
                    int hh = rem >> dhShift;
                    int dd = rem & ((1<<dhShift)-1);
                    int bb = m >> 10, tt = m & 1023;
                    int Hn = 1 << (dShift - dhShift);
                    f16* dst = (which==0) ? Qd : ((which==1) ? Kd : Vd);
                    if (which == 2)
                        dst[((((size_t)bb*Hn + hh) << dhShift) + dd)*L_ + tt] = (f16)v;  // V^T
                    else
                        dst[((((size_t)bb*Hn + hh)*L_ + tt) << dhShift) + dd] = (f16)v;
                    continue;
                }
                size_t off = (size_t)m*N + n;
                if (mode == 1){ C[off] = v + R[off]; }
                else if (mode == 2){
                    v = 0.5f*v*(1.0f + erff(v*0.70710678118654752f));
                    C16[off] = (f16)v;
                } else if (mode == 3){
                    if (flag[0]) ((bf16*)OutRaw)[off] = __float2bfloat16(v);
                    else         ((float*)OutRaw)[off] = v;
                } else C[off] = v;
            }
        }
    }
}

// ---------------- fused LN + f16 GEMM (proj_dn / head only, low N) ----------------
template<int K>
__global__ __launch_bounds__(256) void k_lngemm(const float* __restrict__ A, const f16* __restrict__ W,
        const float* __restrict__ lnw, const float* __restrict__ lnb, int doLN,
        float* __restrict__ C, void* __restrict__ OutRaw,
        const int* __restrict__ flag, int N, int mode)
{
    constexpr int SA = K + 8;
    constexpr int RPT = K/64;
    __shared__ f16 sA[64*SA];
    int tid = threadIdx.x;
    int wave = tid >> 6, lane = tid & 63;
    int wr = wave >> 1, wc = wave & 1;
    int quad = lane >> 4, l15 = lane & 15;
    int bm = blockIdx.y * 64, bn = blockIdx.x * 64;

    float wv_[RPT], bv_[RPT];
    #pragma unroll
    for (int j=0;j<RPT;j++){
        int d = lane*RPT + j;
        wv_[j] = doLN ? lnw[d] : 1.f;
        bv_[j] = doLN ? lnb[d] : 0.f;
    }
    for (int rr=0; rr<16; rr++){
        int row = wave*16 + rr;
        const float* xr = A + (size_t)(bm+row)*K + lane*RPT;
        float v[RPT];
        if (RPT==2){ float2 t = *(const float2*)xr; v[0]=t.x; v[1]=t.y; }
        else       { float4 t = *(const float4*)xr; v[0]=t.x; v[1]=t.y; v[2]=t.z; v[3]=t.w; }
        float mu = 0.f, inv = 1.f;
        if (doLN){
            float s=0.f;
            #pragma unroll
            for (int j=0;j<RPT;j++) s += v[j];
            #pragma unroll
            for (int o=32;o>=1;o>>=1) s += __shfl_xor(s,o);
            mu = s / (float)K;
            float s2=0.f;
            #pragma unroll
            for (int j=0;j<RPT;j++){ float dd=v[j]-mu; s2+=dd*dd; }
            #pragma unroll
            for (int o=32;o>=1;o>>=1) s2 += __shfl_xor(s2,o);
            inv = rsqrtf(s2/(float)K + 1e-5f);
        }
        if (RPT==2){
            half2v h;
            h[0]=(f16)((v[0]-mu)*inv*wv_[0]+bv_[0]);
            h[1]=(f16)((v[1]-mu)*inv*wv_[1]+bv_[1]);
            *(half2v*)&sA[row*SA + lane*2] = h;
        } else {
            half4 h;
            #pragma unroll
            for (int j=0;j<4;j++) h[j]=(f16)((v[j]-mu)*inv*wv_[j]+bv_[j]);
            *(half4*)&sA[row*SA + lane*4] = h;
        }
    }
    __syncthreads();

    f32x4 acc[2][2] = {};
    int n0 = bn + wc*32 + l15;
    bool ok0 = n0 < N, ok1 = (n0+16) < N;
    const f16* w0p = W + (size_t)n0*K + quad*8;
    const f16* w1p = W + (size_t)(n0+16)*K + quad*8;
    #pragma unroll 4
    for (int k0=0;k0<K;k0+=32){
        half8 af[2], wf[2];
        af[0] = *(const half8*)&sA[(wr*32 + l15)*SA + k0 + quad*8];
        af[1] = *(const half8*)&sA[(wr*32 + 16 + l15)*SA + k0 + quad*8];
        wf[0] = ok0 ? *(const half8*)(w0p + k0) : (half8)(f16)0.f;
        wf[1] = ok1 ? *(const half8*)(w1p + k0) : (half8)(f16)0.f;
        #pragma unroll
        for (int i=0;i<2;i++)
            #pragma unroll
            for (int j=0;j<2;j++)
                acc[i][j] = __builtin_amdgcn_mfma_f32_16x16x32_f16(af[i], wf[j], acc[i][j], 0, 0, 0);
    }

    #pragma unroll
    for (int j=0;j<2;j++){
        int n = bn + wc*32 + j*16 + l15;
        if (n >= N) continue;
        #pragma unroll
        for (int i=0;i<2;i++){
            #pragma unroll
            for (int r=0;r<4;r++){
                int m = bm + wr*32 + i*16 + quad*4 + r;
                float v = acc[i][j][r];
                size_t off = (size_t)m*N + n;
                if (mode == 3){
                    if (flag[0]) ((bf16*)OutRaw)[off] = __float2bfloat16(v);
                    else         ((float*)OutRaw)[off] = v;
                } else C[off] = v;
            }
        }
    }
}

// ---------------- MFMA f16 flash, f16 output ----------------
template<int DH>
__global__ __launch_bounds__(256) void k_mflash(const f16* __restrict__ Qh, const f16* __restrict__ Kh,
        const f16* __restrict__ Vt, f16* __restrict__ out, const int* __restrict__ counts,
        float scale)
{
    constexpr int BQ = 64, BK = 64;
    constexpr int RS = DH + 8;
    constexpr int PS = BK + 8;
    __shared__ f16 sQ[BQ*RS];
    __shared__ f16 sK[BK*RS];
    __shared__ f16 sVt[DH*PS];
    __shared__ f16 sP[BQ*PS];

    int x = blockIdx.x, b = x >> 2, h = x & 3;
    int yy = blockIdx.y;
    int qt = (yy < 8) ? yy : 23 - yy;
    int q0 = qt * BQ;
    int tid = threadIdx.x;
    int wv = tid >> 6, lane = tid & 63;
    int quad = lane >> 4, l15 = lane & 15;

    const f16* Qb = Qh + (size_t)x*L_*DH;
    const f16* Kb = Kh + (size_t)x*L_*DH;
    const f16* Vb = Vt + (size_t)x*DH*L_;
    int kcap = counts ? counts[b] : L_;
    int klen = min(kcap, q0 + BQ);

    for (int i = tid; i < BQ*DH/8; i += 256){
        int r = (8*i)/DH, c = (8*i)%DH;
        *(half8*)&sQ[r*RS + c] = *(const half8*)&Qb[(size_t)(q0+r)*DH + c];
    }

    float m[4], l[4];
    #pragma unroll
    for (int r=0;r<4;r++){ m[r] = -1e30f; l[r] = 0.f; }
    f32x4 accO[DH/16] = {};

    for (int k0 = 0; k0 < klen; k0 += BK){
        __syncthreads();
        for (int i = tid; i < BK*DH/8; i += 256){
            int r = (8*i)/DH, c = (8*i)%DH;
            *(half8*)&sK[r*RS + c] = *(const half8*)&Kb[(size_t)(k0+r)*DH + c];
        }
        for (int i = tid; i < DH*BK/8; i += 256){
            int r = (8*i)/BK, c = (8*i)%BK;
            *(half8*)&sVt[r*PS + c] = *(const half8*)&Vb[(size_t)r*L_ + k0 + c];
        }
        __syncthreads();

        half8 af[DH/32];
        #pragma unroll
        for (int ds=0; ds<DH/32; ds++)
            af[ds] = *(const half8*)&sQ[(16*wv + l15)*RS + quad*8 + 32*ds];
        f32x4 accS[4] = {};
        #pragma unroll
        for (int t=0;t<4;t++){
            #pragma unroll
            for (int ds=0; ds<DH/32; ds++){
                half8 bf = *(const half8*)&sK[(16*t + l15)*RS + quad*8 + 32*ds];
                accS[t] = __builtin_amdgcn_mfma_f32_16x16x32_f16(af[ds], bf, accS[t], 0, 0, 0);
            }
        }

        #pragma unroll
        for (int r=0;r<4;r++){
            int qrow = q0 + 16*wv + quad*4 + r;
            float sv[4];
            #pragma unroll
            for (int t=0;t<4;t++){
                float v = accS[t][r]*scale;
                int kp = k0 + 16*t + l15;
                if (kp > qrow || kp >= kcap) v = -1e30f;
                sv[t] = v;
            }
            float rm = fmaxf(fmaxf(sv[0],sv[1]), fmaxf(sv[2],sv[3]));
            rm = fmaxf(rm, __shfl_xor(rm, 1));
            rm = fmaxf(rm, __shfl_xor(rm, 2));
            rm = fmaxf(rm, __shfl_xor(rm, 4));
            rm = fmaxf(rm, __shfl_xor(rm, 8));
            float mn = fmaxf(m[r], rm);
            float al = __expf(m[r] - mn);
            float p0 = __expf(sv[0]-mn), p1 = __expf(sv[1]-mn);
            float p2 = __expf(sv[2]-mn), p3 = __expf(sv[3]-mn);
            float rs = p0+p1+p2+p3;
            rs += __shfl_xor(rs, 1);
            rs += __shfl_xor(rs, 2);
            rs += __shfl_xor(rs, 4);
            rs += __shfl_xor(rs, 8);
            l[r] = l[r]*al + rs;
            m[r] = mn;
            #pragma unroll
            for (int dt=0; dt<DH/16; dt++) accO[dt][r] *= al;
            int prow = 16*wv + quad*4 + r;
            sP[prow*PS + 16*0 + l15] = (f16)p0;
            sP[prow*PS + 16*1 + l15] = (f16)p1;
            sP[prow*PS + 16*2 + l15] = (f16)p2;
            sP[prow*PS + 16*3 + l15] = (f16)p3;
        }

        half8 pf[2];
        #pragma unroll
        for (int ks=0; ks<2; ks++)
            pf[ks] = *(const half8*)&sP[(16*wv + l15)*PS + quad*8 + 32*ks];
        #pragma unroll
        for (int dt=0; dt<DH/16; dt++){
            #pragma unroll
            for (int ks=0; ks<2; ks++){
                half8 bv = *(const half8*)&sVt[(16*dt + l15)*PS + quad*8 + 32*ks];
                accO[dt] = __builtin_amdgcn_mfma_f32_16x16x32_f16(pf[ks], bv, accO[dt], 0, 0, 0);
            }
        }
    }

    #pragma unroll
    for (int r=0;r<4;r++){
        float inv = 1.0f / l[r];
        int qrow = q0 + 16*wv + quad*4 + r;
        #pragma unroll
        for (int dt=0; dt<DH/16; dt++){
            int d = 16*dt + l15;
            out[((size_t)b*L_ + qrow)*(NHEADS*DH) + h*DH + d] = (f16)(accO[dt][r]*inv);
        }
    }
}

// ---------------- router (also zeroes ACC from block 0) ----------------
__global__ __launch_bounds__(64) void k_router(const float* __restrict__ Q, const float* __restrict__ Kr,
        float* __restrict__ p, float* __restrict__ bh, float* __restrict__ acc)
{
    int idx = blockIdx.x;
    int t = idx & (L_-1);
    int lane = threadIdx.x;
    if (idx == 0 && lane < 8) acc[lane] = 0.f;
    float pv;
    if (t == 0){ pv = 1.0f; }
    else {
        const float* qr = Q  + (size_t)idx*DENC;
        const float* kr = Kr + (size_t)(idx-1)*DENC;
        float qq=0.f, kk=0.f, qk=0.f;
        #pragma unroll
        for (int j=0;j<2;j++){
            float qv = qr[lane + j*64], kv = kr[lane + j*64];
            qq += qv*qv; kk += kv*kv; qk += qv*kv;
        }
        #pragma unroll
        for (int o=32;o>=1;o>>=1){ qq += __shfl_xor(qq,o); kk += __shfl_xor(kk,o); qk += __shfl_xor(qk,o); }
        float cosv = qk / (fmaxf(sqrtf(qq),1e-12f)*fmaxf(sqrtf(kk),1e-12f));
        pv = 0.5f*(1.0f - cosv);
        pv = fminf(fmaxf(pv, 0.0f), 1.0f);
    }
    if (lane == 0){ p[idx] = pv; bh[idx] = (pv >= 0.5f) ? 1.0f : 0.0f; }
}

// ---------------- per-batch cumsum + slot map + fused p/bh global sums ----------------
__global__ __launch_bounds__(64) void k_seq(const float* __restrict__ bh, const float* __restrict__ p,
                      int* __restrict__ cidx, int* __restrict__ src, int* __restrict__ counts,
                      float* __restrict__ acc){
    int b = blockIdx.x;
    int lane = threadIdx.x;
    int base = b*L_ + lane*16;
    int h[16];
    int cnt = 0;
    float ps = 0.f;
    #pragma unroll
    for (int j=0;j<16;j++){ h[j] = bh[base+j] > 0.5f; cnt += h[j]; ps += p[base+j]; }
    int inc = cnt;
    #pragma unroll
    for (int o=1;o<64;o<<=1){ int nb = __shfl_up(inc, o); if (lane >= o) inc += nb; }
    int run = inc - cnt;
    #pragma unroll
    for (int j=0;j<16;j++){
        run += h[j];
        int ci = run - 1; if (ci < 0) ci = 0;
        cidx[base+j] = ci;
        if (h[j]) src[b*L_ + run-1] = lane*16 + j;
    }
    float cs = (float)cnt;
    #pragma unroll
    for (int o=32;o>=1;o>>=1){ ps += __shfl_xor(ps,o); cs += __shfl_xor(cs,o); }
    if (lane == 0){ atomicAdd(&acc[0], ps); atomicAdd(&acc[1], cs); }
    if (lane == 63) counts[b] = inc;
}

// ---------------- scatter-compress to f16 (zero-filled) ----------------
__global__ __launch_bounds__(128) void k_scatter2(const float* __restrict__ x, const float* __restrict__ p,
        const int* __restrict__ src, const int* __restrict__ counts,
        f16* __restrict__ comp, float* __restrict__ pcomp)
{
    int s = blockIdx.x & (L_-1), b = blockIdx.x >> 10, d = threadIdx.x;
    int cnt = counts[b];
    f16* crow = comp + ((size_t)b*L_ + s)*DENC;
    if (s < cnt){
        int t = src[b*L_ + s];
        crow[d] = (f16)x[((size_t)b*L_ + t)*DENC + d];
        if (d == 0) pcomp[b*L_ + s] = p[b*L_ + t];
    } else {
        crow[d] = (f16)0.f;
        if (d == 0) pcomp[b*L_ + s] = 0.f;
    }
}

// ---------------- chunk EMA: 3-phase wave scan ----------------
__global__ __launch_bounds__(256) void k_ema2(const float* __restrict__ z, const float* __restrict__ pcomp,
                                              float* __restrict__ zbar){
    __shared__ float sp[L_];
    int blk = blockIdx.x;
    int b = blk >> 5;
    int tid = threadIdx.x, wv = tid >> 6, lane = tid & 63;
    int d = ((blk & 31) << 2) + wv;
    for (int i = tid; i < L_; i += 256){
        float pc = pcomp[b*L_ + i];
        sp[i] = fminf(fmaxf(pc, 1e-4f), 1.0f - 1e-4f);
    }
    __syncthreads();
    const float* zb = z + ((size_t)b*L_)*DENC + d;
    int t0 = lane*16;
    float zv[16];
    #pragma unroll
    for (int i=0;i<16;i++) zv[i] = zb[(size_t)(t0+i)*DENC];
    float A = 1.f, Bv = 0.f;
    #pragma unroll
    for (int i=0;i<16;i++){
        int t = t0 + i;
        float pc = sp[t];
        float a  = (t==0) ? 0.f : (1.f - pc);
        float bb = (t==0) ? zv[i] : pc*zv[i];
        A = a*A;
        Bv = a*Bv + bb;
    }
    #pragma unroll
    for (int off=1; off<64; off<<=1){
        float Ap = __shfl_up(A, off);
        float Bp = __shfl_up(Bv, off);
        if (lane >= off){ Bv = A*Bp + Bv; A = A*Ap; }
    }
    float sin_ = __shfl_up(Bv, 1);
    if (lane == 0) sin_ = 0.f;
    float s = sin_;
    float* ob = zbar + ((size_t)b*L_)*DENC + d;
    #pragma unroll
    for (int i=0;i<16;i++){
        int t = t0 + i;
        float pc = sp[t];
        float a  = (t==0) ? 0.f : (1.f - pc);
        float bb = (t==0) ? zv[i] : pc*zv[i];
        s = a*s + bb;
        ob[(size_t)t*DENC] = s;
    }
}

__global__ void k_combine(float* __restrict__ x, const float* __restrict__ zbar, const int* __restrict__ cidx){
    int i = blockIdx.x*256 + threadIdx.x;
    int row = i >> 7, d = i & 127;
    int b = row >> 10;
    int ci = cidx[row];
    x[i] += zbar[((size_t)b*L_ + ci)*DENC + d];
}

__global__ void k_loss(const float* __restrict__ acc, void* __restrict__ out, const int* __restrict__ flag){
    float G = acc[0] / (float)BL;
    float F = acc[1] / (float)BL;
    float ratio = 1.2f*(5.0f*F*G + (1.0f-F)*(1.0f-G));
    if (flag[0]) ((bf16*)out)[(size_t)BL*VOCAB] = __float2bfloat16(ratio);
    else         ((float*)out)[(size_t)BL*VOCAB] = ratio;
}

// =========================================================================
extern "C" void kernel_launch(void* const* d_in, const int* in_sizes, int n_in,
                              void* d_out, int out_size, void* d_ws, size_t ws_size,
                              hipStream_t stream) {
    (void)out_size; (void)ws_size;
    const int* byte_ids = (const int*)d_in[0];

    float* ws = (float*)d_ws;
    size_t off = 0;
    int* FLAG = (int*)ws; off += 16;
    float* W32 = ws + off;

    k_detect<<<1, 64, 0, stream>>>(d_in[1], FLAG);

    CvtArgs ca;
    const float* w32[32];
    unsigned woff = 0;
    for (int i = 1; i < n_in && i < 32; i++){
        w32[i] = W32 + woff;
        ca.src[i-1] = d_in[i];
        ca.offs[i-1] = woff;
        woff += (unsigned)in_sizes[i];
    }
    ca.offs[31] = woff;
    off += woff;
    f16* W16h = (f16*)(ws + off); off += (woff+1)/2;
    const f16* w16[32];
    for (int i = 1; i < n_in && i < 32; i++) w16[i] = W16h + ca.offs[i-1];
    k_cvt_all<<<2048, 256, 0, stream>>>(ca, W32, W16h, (int)woff, FLAG);

    const float* embed    = w32[1];
    const float* wq       = w32[2];
    const float* wk       = w32[3];
    const float* norm_w   = w32[6];
    const float* norm_b   = w32[7];

    float* X    = ws + off; off += (size_t)BL*DENC;
    float* QKVf = ws + off; off += (size_t)BL*3*DMAIN;
    float* ATTf = ws + off; off += (size_t)BL*DMAIN;
    float* Hf   = ws + off; off += (size_t)BL*2*DMAIN;
    float* LNf  = ws + off; off += (size_t)BL*DMAIN;
    float* Z    = ws + off; off += (size_t)BL*DMAIN;
    float* COMPf= ws + off; off += (size_t)BL*DENC;
    float* P    = ws + off; off += BL;
    float* BH   = ws + off; off += BL;
    float* PCOMP= ws + off; off += BL;
    float* ACC  = ws + off; off += 8;
    int* CIDX   = (int*)(ws + off); off += BL;
    int* SRC    = (int*)(ws + off); off += BL;
    int* COUNTS = (int*)(ws + off); off += 64;

    f16* QKV16 = (f16*)QKVf;
    f16* ATT16 = (f16*)ATTf;
    f16* H16   = (f16*)Hf;
    f16* LN16  = (f16*)LNf;
    f16* COMP16= (f16*)COMPf;
    float* Qr  = ATTf;
    float* Kr  = Hf;
    float* ZDN = QKVf;
    float* ZBAR= QKVf + (size_t)BL*DENC;

    auto hgemm = [&](int K, int BM, const f16* A, const f16* W, const float* R, float* C, f16* C16,
                     void* Ob, int N, int mode, f16* Qd, f16* Kd, f16* Vd, int dS, int dhS){
        dim3 g((N+63)/64, BL/BM);
        if (BM == 128){
            if (K == 128)      k_hgemm<128,128><<<g,256,0,stream>>>(A, W, R, C, C16, Ob, FLAG, N, mode, Qd, Kd, Vd, dS, dhS);
            else if (K == 256) k_hgemm<256,128><<<g,256,0,stream>>>(A, W, R, C, C16, Ob, FLAG, N, mode, Qd, Kd, Vd, dS, dhS);
            else               k_hgemm<512,128><<<g,256,0,stream>>>(A, W, R, C, C16, Ob, FLAG, N, mode, Qd, Kd, Vd, dS, dhS);
        } else {
            if (K == 128)      k_hgemm<128,64><<<g,256,0,stream>>>(A, W, R, C, C16, Ob, FLAG, N, mode, Qd, Kd, Vd, dS, dhS);
            else if (K == 256) k_hgemm<256,64><<<g,256,0,stream>>>(A, W, R, C, C16, Ob, FLAG, N, mode, Qd, Kd, Vd, dS, dhS);
            else               k_hgemm<512,64><<<g,256,0,stream>>>(A, W, R, C, C16, Ob, FLAG, N, mode, Qd, Kd, Vd, dS, dhS);
        }
    };

    auto block128 = [&](float* Xs, const float* l1w, const float* l1b, const f16* qkvw, const f16* wo,
                        const float* l2w, const float* l2b, const f16* w1, const f16* w2){
        k_ln16<128><<<BL/4,256,0,stream>>>(Xs, l1w, l1b, LN16);
        hgemm(128, 128, LN16, qkvw, nullptr, nullptr, nullptr, nullptr, 3*DENC, 5,
              QKV16, QKV16 + (size_t)BL*DENC, QKV16 + (size_t)2*BL*DENC, 7, 5);
        k_mflash<32><<<dim3(B_*NHEADS,16),256,0,stream>>>(QKV16, QKV16 + (size_t)BL*DENC,
                                                          QKV16 + (size_t)2*BL*DENC,
                                                          ATT16, nullptr, 0.17677669529663687f);
        hgemm(128, 64, ATT16, wo, Xs, Xs, nullptr, nullptr, DENC, 1, nullptr, nullptr, nullptr, 0, 0);
        k_ln16<128><<<BL/4,256,0,stream>>>(Xs, l2w, l2b, LN16);
        hgemm(128, 64, LN16, w1, nullptr, nullptr, H16, nullptr, 2*DENC, 2, nullptr, nullptr, nullptr, 0, 0);
        hgemm(256, 64, H16, w2, Xs, Xs, nullptr, nullptr, DENC, 1, nullptr, nullptr, nullptr, 0, 0);
    };
    auto block_main = [&](float* Xs, const float* l1w, const float* l1b, const f16* qkvw, const f16* wo,
                          const float* l2w, const float* l2b, const f16* w1, const f16* w2){
        k_ln16<256><<<BL/4,256,0,stream>>>(Xs, l1w, l1b, LN16);
        hgemm(256, 128, LN16, qkvw, nullptr, nullptr, nullptr, nullptr, 3*DMAIN, 5,
              QKV16, QKV16 + (size_t)BL*DMAIN, QKV16 + (size_t)2*BL*DMAIN, 8, 6);
        k_mflash<64><<<dim3(B_*NHEADS,16),256,0,stream>>>(QKV16, QKV16 + (size_t)BL*DMAIN,
                                                          QKV16 + (size_t)2*BL*DMAIN,
                                                          ATT16, COUNTS, 0.125f);
        hgemm(256, 64, ATT16, wo, Xs, Xs, nullptr, nullptr, DMAIN, 1, nullptr, nullptr, nullptr, 0, 0);
        k_ln16<256><<<BL/4,256,0,stream>>>(Xs, l2w, l2b, LN16);
        hgemm(256, 128, LN16, w1, nullptr, nullptr, H16, nullptr, 2*DMAIN, 2, nullptr, nullptr, nullptr, 0, 0);
        hgemm(512, 64, H16, w2, Xs, Xs, nullptr, nullptr, DMAIN, 1, nullptr, nullptr, nullptr, 0, 0);
    };

    // ---- embed + encoder ----
    k_embed<<<BL*DENC/256, 256, 0, stream>>>(byte_ids, embed, X);
    for (int i = 0; i < 3; i++)
        block128(X, w32[8] + i*DENC, w32[9] + i*DENC, w16[10] + (size_t)i*3*DENC*DENC,
                 w16[11] + (size_t)i*DENC*DENC, w32[12] + i*DENC, w32[13] + i*DENC,
                 w16[14] + (size_t)i*2*DENC*DENC, w16[15] + (size_t)i*2*DENC*DENC);

    // ---- routing (f32) ----
    k_gemm2<<<dim3(4, BL/64), 256, 0, stream>>>(X, wq, wk, Qr, Kr, DENC);
    k_router<<<BL, 64, 0, stream>>>(Qr, Kr, P, BH, ACC);
    k_seq<<<B_, 64, 0, stream>>>(BH, P, CIDX, SRC, COUNTS, ACC);
    k_scatter2<<<BL, 128, 0, stream>>>(X, P, SRC, COUNTS, COMP16, PCOMP);

    // ---- main stack on compressed ----
    hgemm(128, 64, COMP16, w16[4], nullptr, Z, nullptr, nullptr, DMAIN, 0, nullptr, nullptr, nullptr, 0, 0);
    for (int i = 0; i < 6; i++)
        block_main(Z, w32[16] + i*DMAIN, w32[17] + i*DMAIN, w16[18] + (size_t)i*3*DMAIN*DMAIN,
                   w16[19] + (size_t)i*DMAIN*DMAIN, w32[20] + i*DMAIN, w32[21] + i*DMAIN,
                   w16[22] + (size_t)i*2*DMAIN*DMAIN, w16[23] + (size_t)i*2*DMAIN*DMAIN);
    k_lngemm<256><<<dim3(2, BL/64), 256, 0, stream>>>(Z, w16[5], nullptr, nullptr, 0,
                                                      ZDN, nullptr, FLAG, DENC, 0);   // proj_dn

    // ---- EMA + dechunk combine ----
    k_ema2<<<256, 256, 0, stream>>>(ZDN, PCOMP, ZBAR);
    k_combine<<<BL*DENC/256, 256, 0, stream>>>(X, ZBAR, CIDX);

    // ---- decoder ----
    for (int i = 0; i < 3; i++)
        block128(X, w32[24] + i*DENC, w32[25] + i*DENC, w16[26] + (size_t)i*3*DENC*DENC,
                 w16[27] + (size_t)i*DENC*DENC, w32[28] + i*DENC, w32[29] + i*DENC,
                 w16[30] + (size_t)i*2*DENC*DENC, w16[31] + (size_t)i*2*DENC*DENC);

    // ---- final LN + tied head + loss ----
    k_lngemm<128><<<dim3(5, BL/64), 256, 0, stream>>>(X, w16[1], norm_w, norm_b, 1,
                                                      nullptr, d_out, FLAG, VOCAB, 3);
    k_loss<<<1,1,0,stream>>>(ACC, d_out, FLAG);
}

// Round 11
// 1257.483 us; speedup vs baseline: 1.0371x; 1.0371x over previous
//
#include <hip/hip_runtime.h>
#include <hip/hip_bf16.h>

#define B_ 8
#define L_ 1024
#define BL (B_*L_)
#define DENC 128
#define DMAIN 256
#define VOCAB 260
#define NHEADS 4

typedef __hip_bfloat16 bf16;
typedef _Float16 f16;
typedef f16 half8 __attribute__((ext_vector_type(8)));
typedef f16 half4 __attribute__((ext_vector_type(4)));
typedef f16 half2v __attribute__((ext_vector_type(2)));
typedef float f32x4 __attribute__((ext_vector_type(4)));

// ---------------- dtype detector ----------------
__global__ __launch_bounds__(64) void k_detect(const void* __restrict__ emb, int* __restrict__ flag){
    int lane = threadIdx.x;
    const unsigned short* u = (const unsigned short*)emb;
    int bad = 0;
    #pragma unroll
    for (int j = 0; j < 4; j++){
        unsigned short h = u[lane + 64*j];
        bf16 t = *(const bf16*)&h;
        float v = __bfloat162float(t);
        if (!(fabsf(v) < 1e4f)) bad++;
    }
    #pragma unroll
    for (int o = 32; o >= 1; o >>= 1) bad += __shfl_xor(bad, o);
    if (lane == 0) flag[0] = (bad == 0) ? 1 : 0;
}

// ---------------- fused convert: f16 copy always; f32 master only where needed ----------------
struct CvtArgs {
    const void* src[31];
    unsigned offs[32];
};
__global__ void k_cvt_all(CvtArgs a, float* __restrict__ dst, f16* __restrict__ dst16,
                          int total, const int* __restrict__ flag, unsigned f32mask){
    int isbf = flag[0];
    for (int i = blockIdx.x*256 + threadIdx.x; i < total; i += gridDim.x*256){
        int lo = 0, hi = 30;
        while (lo < hi){ int mid = (lo+hi+1)>>1; if (a.offs[mid] <= (unsigned)i) lo = mid; else hi = mid-1; }
        int j = i - (int)a.offs[lo];
        float v = isbf ? __bfloat162float(((const bf16*)a.src[lo])[j])
                       : ((const float*)a.src[lo])[j];
        if ((f32mask >> lo) & 1u) dst[i] = v;
        dst16[i] = (f16)v;
    }
}

// ---------------- embed gather ----------------
__global__ void k_embed(const int* __restrict__ ids, const float* __restrict__ emb, float* __restrict__ x){
    int i = blockIdx.x*256 + threadIdx.x;
    int row = i >> 7, d = i & 127;
    x[i] = emb[ids[row]*DENC + d];
}

// ---------------- layernorm: f32 in -> f16 out, 4 rows/block ----------------
template<int D>
__global__ __launch_bounds__(256) void k_ln16(const float* __restrict__ x, const float* __restrict__ w,
                                              const float* __restrict__ b, f16* __restrict__ y){
    int row = blockIdx.x*4 + (threadIdx.x >> 6);
    int lane = threadIdx.x & 63;
    const float* xr = x + (size_t)row*D;
    float v[D/64];
    float s = 0.f;
    #pragma unroll
    for (int j=0;j<D/64;j++){ v[j] = xr[lane + j*64]; s += v[j]; }
    #pragma unroll
    for (int o=32;o>=1;o>>=1) s += __shfl_xor(s,o);
    float mu = s / (float)D;
    float s2 = 0.f;
    #pragma unroll
    for (int j=0;j<D/64;j++){ float dd = v[j]-mu; s2 += dd*dd; }
    #pragma unroll
    for (int o=32;o>=1;o>>=1) s2 += __shfl_xor(s2,o);
    float inv = rsqrtf(s2/(float)D + 1e-5f);
    f16* yr = y + (size_t)row*D;
    #pragma unroll
    for (int j=0;j<D/64;j++){
        int d = lane + j*64;
        yr[d] = (f16)((v[j]-mu)*inv*w[d] + b[d]);
    }
}

// ---------------- f32 vector GEMM: fused wq/wk (router only) ----------------
#define GBM 64
#define GBN 64
#define GBK 32
__global__ __launch_bounds__(256) void k_gemm2(const float* __restrict__ A, const float* __restrict__ Wq,
        const float* __restrict__ Wk, float* __restrict__ Cq, float* __restrict__ Ck, int K)
{
    __shared__ float As[GBK][GBM+4];
    __shared__ float Ws[GBK][GBN+4];
    int tid = threadIdx.x;
    int bm = blockIdx.y * GBM;
    int bn = blockIdx.x * GBN;
    int tx = tid & 15, ty = tid >> 4;
    float acc[4][4] = {};
    for (int k0 = 0; k0 < K; k0 += GBK){
        #pragma unroll
        for (int i = tid; i < GBM*GBK; i += 256){
            int m = i >> 5, kk = i & 31;
            As[kk][m] = A[(size_t)(bm+m)*K + k0 + kk];
        }
        #pragma unroll
        for (int i = tid; i < GBN*GBK; i += 256){
            int n = i >> 5, kk = i & 31;
            int gn = bn + n;
            const float* W = (gn < 128) ? Wq : Wk;
            int wr = gn & 127;
            Ws[kk][n] = W[(size_t)wr*K + k0 + kk];
        }
        __syncthreads();
        #pragma unroll
        for (int kk = 0; kk < GBK; kk++){
            float a0[4], w0[4];
            *(float4*)a0 = *(const float4*)&As[kk][ty*4];
            *(float4*)w0 = *(const float4*)&Ws[kk][tx*4];
            #pragma unroll
            for (int i=0;i<4;i++)
                #pragma unroll
                for (int j=0;j<4;j++) acc[i][j] += a0[i]*w0[j];
        }
        __syncthreads();
    }
    #pragma unroll
    for (int i=0;i<4;i++){
        int m = bm + ty*4 + i;
        #pragma unroll
        for (int j=0;j<4;j++){
            int n = bn + tx*4 + j;
            float* C = (n < 128) ? Cq : Ck;
            C[(size_t)m*128 + (n & 127)] = acc[i][j];
        }
    }
}

// ---------------- f16 MFMA GEMM, BK=64, [chunk][row] LDS (conflict-free), 64x64 tile ----------------
// modes: 0 C f32, 1 C = R + A@W^T, 2 gelu->C16 f16, 3 out-store, 5 split-head QKV f16 (V^T)
template<int K>
__global__ __launch_bounds__(256) void k_hgemm(const f16* __restrict__ A, const f16* __restrict__ W,
        const float* __restrict__ R, float* __restrict__ C, f16* __restrict__ C16,
        void* __restrict__ OutRaw, const int* __restrict__ flag, int N, int mode,
        f16* __restrict__ Qd, f16* __restrict__ Kd, f16* __restrict__ Vd,
        int dShift, int dhShift)
{
    __shared__ half8 As[8][64];    // [k-chunk][row]
    __shared__ half8 Ws[8][64];
    int tid = threadIdx.x;
    int wave = tid >> 6, lane = tid & 63;
    int wr = wave >> 1, wc = wave & 1;
    int quad = lane >> 4, l15 = lane & 15;
    int bm = blockIdx.y * 64, bn = blockIdx.x * 64;

    f32x4 acc[2][2] = {};
    int srow = tid >> 3;           // 0..31
    int sch  = tid & 7;            // chunk 0..7
    const f16* ap0 = A + (size_t)(bm + srow)*K + sch*8;
    const f16* ap1 = A + (size_t)(bm + srow + 32)*K + sch*8;
    int gn0 = bn + srow, gn1 = bn + srow + 32;
    const f16* wp0 = W + (size_t)gn0*K + sch*8;
    const f16* wp1 = W + (size_t)gn1*K + sch*8;
    bool wok0 = gn0 < N, wok1 = gn1 < N;

    for (int k0 = 0; k0 < K; k0 += 64){
        __syncthreads();
        As[sch][srow]      = *(const half8*)(ap0 + k0);
        As[sch][srow + 32] = *(const half8*)(ap1 + k0);
        Ws[sch][srow]      = wok0 ? *(const half8*)(wp0 + k0) : (half8)(f16)0.f;
        Ws[sch][srow + 32] = wok1 ? *(const half8*)(wp1 + k0) : (half8)(f16)0.f;
        __syncthreads();
        #pragma unroll
        for (int ks = 0; ks < 2; ks++){
            half8 af[2], wf[2];
            af[0] = As[ks*4 + quad][wr*32 + l15];
            af[1] = As[ks*4 + quad][wr*32 + 16 + l15];
            wf[0] = Ws[ks*4 + quad][wc*32 + l15];
            wf[1] = Ws[ks*4 + quad][wc*32 + 16 + l15];
            #pragma unroll
            for (int i=0;i<2;i++)
                #pragma unroll
                for (int j=0;j<2;j++)
                    acc[i][j] = __builtin_amdgcn_mfma_f32_16x16x32_f16(af[i], wf[j], acc[i][j], 0, 0, 0);
        }
    }

    #pragma unroll
    for (int j=0;j<2;j++){
        int n = bn + wc*32 + j*16 + l15;
        if (n >= N) continue;
        #pragma unroll
        for (int i=0;i<2;i++){
            #pragma unroll
            for (int r=0;r<4;r++){
                int m = bm + wr*32 + i*16 + quad*4 + r;
                float v = acc[i][j][r];
                if (mode == 5){
                    int which = n >> dShift;
                    int rem = n & ((1<<dShift)-1);
                    int hh = rem >> dhShift;
                    int dd = rem & ((1<<dhShift)-1);
                    int bb = m >> 10, tt = m & 1023;
                    int Hn = 1 << (dShift - dhShift);
                    f16* dst = (which==0) ? Qd : ((which==1) ? Kd : Vd);
                    if (which == 2)
                        dst[((((size_t)bb*Hn + hh) << dhShift) + dd)*L_ + tt] = (f16)v;  // V^T
                    else
                        dst[((((size_t)bb*Hn + hh)*L_ + tt) << dhShift) + dd] = (f16)v;
                    continue;
                }
                size_t off = (size_t)m*N + n;
                if (mode == 1){ C[off] = v + R[off]; }
                else if (mode == 2){
                    v = 0.5f*v*(1.0f + erff(v*0.70710678118654752f));
                    C16[off] = (f16)v;
                } else if (mode == 3){
                    if (flag[0]) ((bf16*)OutRaw)[off] = __float2bfloat16(v);
                    else         ((float*)OutRaw)[off] = v;
                } else C[off] = v;
            }
        }
    }
}

// ---------------- fused LN + f16 GEMM (proj_dn / head only, low N) ----------------
template<int K>
__global__ __launch_bounds__(256) void k_lngemm(const float* __restrict__ A, const f16* __restrict__ W,
        const float* __restrict__ lnw, const float* __restrict__ lnb, int doLN,
        float* __restrict__ C, void* __restrict__ OutRaw,
        const int* __restrict__ flag, int N, int mode)
{
    constexpr int SA = K + 8;
    constexpr int RPT = K/64;
    __shared__ f16 sA[64*SA];
    int tid = threadIdx.x;
    int wave = tid >> 6, lane = tid & 63;
    int wr = wave >> 1, wc = wave & 1;
    int quad = lane >> 4, l15 = lane & 15;
    int bm = blockIdx.y * 64, bn = blockIdx.x * 64;

    float wv_[RPT], bv_[RPT];
    #pragma unroll
    for (int j=0;j<RPT;j++){
        int d = lane*RPT + j;
        wv_[j] = doLN ? lnw[d] : 1.f;
        bv_[j] = doLN ? lnb[d] : 0.f;
    }
    for (int rr=0; rr<16; rr++){
        int row = wave*16 + rr;
        const float* xr = A + (size_t)(bm+row)*K + lane*RPT;
        float v[RPT];
        if (RPT==2){ float2 t = *(const float2*)xr; v[0]=t.x; v[1]=t.y; }
        else       { float4 t = *(const float4*)xr; v[0]=t.x; v[1]=t.y; v[2]=t.z; v[3]=t.w; }
        float mu = 0.f, inv = 1.f;
        if (doLN){
            float s=0.f;
            #pragma unroll
            for (int j=0;j<RPT;j++) s += v[j];
            #pragma unroll
            for (int o=32;o>=1;o>>=1) s += __shfl_xor(s,o);
            mu = s / (float)K;
            float s2=0.f;
            #pragma unroll
            for (int j=0;j<RPT;j++){ float dd=v[j]-mu; s2+=dd*dd; }
            #pragma unroll
            for (int o=32;o>=1;o>>=1) s2 += __shfl_xor(s2,o);
            inv = rsqrtf(s2/(float)K + 1e-5f);
        }
        if (RPT==2){
            half2v h;
            h[0]=(f16)((v[0]-mu)*inv*wv_[0]+bv_[0]);
            h[1]=(f16)((v[1]-mu)*inv*wv_[1]+bv_[1]);
            *(half2v*)&sA[row*SA + lane*2] = h;
        } else {
            half4 h;
            #pragma unroll
            for (int j=0;j<4;j++) h[j]=(f16)((v[j]-mu)*inv*wv_[j]+bv_[j]);
            *(half4*)&sA[row*SA + lane*4] = h;
        }
    }
    __syncthreads();

    f32x4 acc[2][2] = {};
    int n0 = bn + wc*32 + l15;
    bool ok0 = n0 < N, ok1 = (n0+16) < N;
    const f16* w0p = W + (size_t)n0*K + quad*8;
    const f16* w1p = W + (size_t)(n0+16)*K + quad*8;
    #pragma unroll 4
    for (int k0=0;k0<K;k0+=32){
        half8 af[2], wf[2];
        af[0] = *(const half8*)&sA[(wr*32 + l15)*SA + k0 + quad*8];
        af[1] = *(const half8*)&sA[(wr*32 + 16 + l15)*SA + k0 + quad*8];
        wf[0] = ok0 ? *(const half8*)(w0p + k0) : (half8)(f16)0.f;
        wf[1] = ok1 ? *(const half8*)(w1p + k0) : (half8)(f16)0.f;
        #pragma unroll
        for (int i=0;i<2;i++)
            #pragma unroll
            for (int j=0;j<2;j++)
                acc[i][j] = __builtin_amdgcn_mfma_f32_16x16x32_f16(af[i], wf[j], acc[i][j], 0, 0, 0);
    }

    #pragma unroll
    for (int j=0;j<2;j++){
        int n = bn + wc*32 + j*16 + l15;
        if (n >= N) continue;
        #pragma unroll
        for (int i=0;i<2;i++){
            #pragma unroll
            for (int r=0;r<4;r++){
                int m = bm + wr*32 + i*16 + quad*4 + r;
                float v = acc[i][j][r];
                size_t off = (size_t)m*N + n;
                if (mode == 3){
                    if (flag[0]) ((bf16*)OutRaw)[off] = __float2bfloat16(v);
                    else         ((float*)OutRaw)[off] = v;
                } else C[off] = v;
            }
        }
    }
}

// ---------------- MFMA f16 flash, f16 output ----------------
template<int DH>
__global__ __launch_bounds__(256) void k_mflash(const f16* __restrict__ Qh, const f16* __restrict__ Kh,
        const f16* __restrict__ Vt, f16* __restrict__ out, const int* __restrict__ counts,
        float scale)
{
    constexpr int BQ = 64, BK = 64;
    constexpr int RS = DH + 8;
    constexpr int PS = BK + 8;
    __shared__ f16 sQ[BQ*RS];
    __shared__ f16 sK[BK*RS];
    __shared__ f16 sVt[DH*PS];
    __shared__ f16 sP[BQ*PS];

    int x = blockIdx.x, b = x >> 2, h = x & 3;
    int yy = blockIdx.y;
    int qt = (yy < 8) ? yy : 23 - yy;
    int q0 = qt * BQ;
    int tid = threadIdx.x;
    int wv = tid >> 6, lane = tid & 63;
    int quad = lane >> 4, l15 = lane & 15;

    const f16* Qb = Qh + (size_t)x*L_*DH;
    const f16* Kb = Kh + (size_t)x*L_*DH;
    const f16* Vb = Vt + (size_t)x*DH*L_;
    int kcap = counts ? counts[b] : L_;
    int klen = min(kcap, q0 + BQ);

    for (int i = tid; i < BQ*DH/8; i += 256){
        int r = (8*i)/DH, c = (8*i)%DH;
        *(half8*)&sQ[r*RS + c] = *(const half8*)&Qb[(size_t)(q0+r)*DH + c];
    }

    float m[4], l[4];
    #pragma unroll
    for (int r=0;r<4;r++){ m[r] = -1e30f; l[r] = 0.f; }
    f32x4 accO[DH/16] = {};

    for (int k0 = 0; k0 < klen; k0 += BK){
        __syncthreads();
        for (int i = tid; i < BK*DH/8; i += 256){
            int r = (8*i)/DH, c = (8*i)%DH;
            *(half8*)&sK[r*RS + c] = *(const half8*)&Kb[(size_t)(k0+r)*DH + c];
        }
        for (int i = tid; i < DH*BK/8; i += 256){
            int r = (8*i)/BK, c = (8*i)%BK;
            *(half8*)&sVt[r*PS + c] = *(const half8*)&Vb[(size_t)r*L_ + k0 + c];
        }
        __syncthreads();

        half8 af[DH/32];
        #pragma unroll
        for (int ds=0; ds<DH/32; ds++)
            af[ds] = *(const half8*)&sQ[(16*wv + l15)*RS + quad*8 + 32*ds];
        f32x4 accS[4] = {};
        #pragma unroll
        for (int t=0;t<4;t++){
            #pragma unroll
            for (int ds=0; ds<DH/32; ds++){
                half8 bf = *(const half8*)&sK[(16*t + l15)*RS + quad*8 + 32*ds];
                accS[t] = __builtin_amdgcn_mfma_f32_16x16x32_f16(af[ds], bf, accS[t], 0, 0, 0);
            }
        }

        #pragma unroll
        for (int r=0;r<4;r++){
            int qrow = q0 + 16*wv + quad*4 + r;
            float sv[4];
            #pragma unroll
            for (int t=0;t<4;t++){
                float v = accS[t][r]*scale;
                int kp = k0 + 16*t + l15;
                if (kp > qrow || kp >= kcap) v = -1e30f;
                sv[t] = v;
            }
            float rm = fmaxf(fmaxf(sv[0],sv[1]), fmaxf(sv[2],sv[3]));
            rm = fmaxf(rm, __shfl_xor(rm, 1));
            rm = fmaxf(rm, __shfl_xor(rm, 2));
            rm = fmaxf(rm, __shfl_xor(rm, 4));
            rm = fmaxf(rm, __shfl_xor(rm, 8));
            float mn = fmaxf(m[r], rm);
            float al = __expf(m[r] - mn);
            float p0 = __expf(sv[0]-mn), p1 = __expf(sv[1]-mn);
            float p2 = __expf(sv[2]-mn), p3 = __expf(sv[3]-mn);
            float rs = p0+p1+p2+p3;
            rs += __shfl_xor(rs, 1);
            rs += __shfl_xor(rs, 2);
            rs += __shfl_xor(rs, 4);
            rs += __shfl_xor(rs, 8);
            l[r] = l[r]*al + rs;
            m[r] = mn;
            #pragma unroll
            for (int dt=0; dt<DH/16; dt++) accO[dt][r] *= al;
            int prow = 16*wv + quad*4 + r;
            sP[prow*PS + 16*0 + l15] = (f16)p0;
            sP[prow*PS + 16*1 + l15] = (f16)p1;
            sP[prow*PS + 16*2 + l15] = (f16)p2;
            sP[prow*PS + 16*3 + l15] = (f16)p3;
        }

        half8 pf[2];
        #pragma unroll
        for (int ks=0; ks<2; ks++)
            pf[ks] = *(const half8*)&sP[(16*wv + l15)*PS + quad*8 + 32*ks];
        #pragma unroll
        for (int dt=0; dt<DH/16; dt++){
            #pragma unroll
            for (int ks=0; ks<2; ks++){
                half8 bv = *(const half8*)&sVt[(16*dt + l15)*PS + quad*8 + 32*ks];
                accO[dt] = __builtin_amdgcn_mfma_f32_16x16x32_f16(pf[ks], bv, accO[dt], 0, 0, 0);
            }
        }
    }

    #pragma unroll
    for (int r=0;r<4;r++){
        float inv = 1.0f / l[r];
        int qrow = q0 + 16*wv + quad*4 + r;
        #pragma unroll
        for (int dt=0; dt<DH/16; dt++){
            int d = 16*dt + l15;
            out[((size_t)b*L_ + qrow)*(NHEADS*DH) + h*DH + d] = (f16)(accO[dt][r]*inv);
        }
    }
}

// ---------------- router (also zeroes ACC from block 0) ----------------
__global__ __launch_bounds__(64) void k_router(const float* __restrict__ Q, const float* __restrict__ Kr,
        float* __restrict__ p, float* __restrict__ bh, float* __restrict__ acc)
{
    int idx = blockIdx.x;
    int t = idx & (L_-1);
    int lane = threadIdx.x;
    if (idx == 0 && lane < 8) acc[lane] = 0.f;
    float pv;
    if (t == 0){ pv = 1.0f; }
    else {
        const float* qr = Q  + (size_t)idx*DENC;
        const float* kr = Kr + (size_t)(idx-1)*DENC;
        float qq=0.f, kk=0.f, qk=0.f;
        #pragma unroll
        for (int j=0;j<2;j++){
            float qv = qr[lane + j*64], kv = kr[lane + j*64];
            qq += qv*qv; kk += kv*kv; qk += qv*kv;
        }
        #pragma unroll
        for (int o=32;o>=1;o>>=1){ qq += __shfl_xor(qq,o); kk += __shfl_xor(kk,o); qk += __shfl_xor(qk,o); }
        float cosv = qk / (fmaxf(sqrtf(qq),1e-12f)*fmaxf(sqrtf(kk),1e-12f));
        pv = 0.5f*(1.0f - cosv);
        pv = fminf(fmaxf(pv, 0.0f), 1.0f);
    }
    if (lane == 0){ p[idx] = pv; bh[idx] = (pv >= 0.5f) ? 1.0f : 0.0f; }
}

// ---------------- per-batch cumsum + slot map + fused p/bh global sums ----------------
__global__ __launch_bounds__(64) void k_seq(const float* __restrict__ bh, const float* __restrict__ p,
                      int* __restrict__ cidx, int* __restrict__ src, int* __restrict__ counts,
                      float* __restrict__ acc){
    int b = blockIdx.x;
    int lane = threadIdx.x;
    int base = b*L_ + lane*16;
    int h[16];
    int cnt = 0;
    float ps = 0.f;
    #pragma unroll
    for (int j=0;j<16;j++){ h[j] = bh[base+j] > 0.5f; cnt += h[j]; ps += p[base+j]; }
    int inc = cnt;
    #pragma unroll
    for (int o=1;o<64;o<<=1){ int nb = __shfl_up(inc, o); if (lane >= o) inc += nb; }
    int run = inc - cnt;
    #pragma unroll
    for (int j=0;j<16;j++){
        run += h[j];
        int ci = run - 1; if (ci < 0) ci = 0;
        cidx[base+j] = ci;
        if (h[j]) src[b*L_ + run-1] = lane*16 + j;
    }
    float cs = (float)cnt;
    #pragma unroll
    for (int o=32;o>=1;o>>=1){ ps += __shfl_xor(ps,o); cs += __shfl_xor(cs,o); }
    if (lane == 0){ atomicAdd(&acc[0], ps); atomicAdd(&acc[1], cs); }
    if (lane == 63) counts[b] = inc;
}

// ---------------- scatter-compress to f16 (zero-filled) ----------------
__global__ __launch_bounds__(128) void k_scatter2(const float* __restrict__ x, const float* __restrict__ p,
        const int* __restrict__ src, const int* __restrict__ counts,
        f16* __restrict__ comp, float* __restrict__ pcomp)
{
    int s = blockIdx.x & (L_-1), b = blockIdx.x >> 10, d = threadIdx.x;
    int cnt = counts[b];
    f16* crow = comp + ((size_t)b*L_ + s)*DENC;
    if (s < cnt){
        int t = src[b*L_ + s];
        crow[d] = (f16)x[((size_t)b*L_ + t)*DENC + d];
        if (d == 0) pcomp[b*L_ + s] = p[b*L_ + t];
    } else {
        crow[d] = (f16)0.f;
        if (d == 0) pcomp[b*L_ + s] = 0.f;
    }
}

// ---------------- chunk EMA: 3-phase wave scan ----------------
__global__ __launch_bounds__(256) void k_ema2(const float* __restrict__ z, const float* __restrict__ pcomp,
                                              float* __restrict__ zbar){
    __shared__ float sp[L_];
    int blk = blockIdx.x;
    int b = blk >> 5;
    int tid = threadIdx.x, wv = tid >> 6, lane = tid & 63;
    int d = ((blk & 31) << 2) + wv;
    for (int i = tid; i < L_; i += 256){
        float pc = pcomp[b*L_ + i];
        sp[i] = fminf(fmaxf(pc, 1e-4f), 1.0f - 1e-4f);
    }
    __syncthreads();
    const float* zb = z + ((size_t)b*L_)*DENC + d;
    int t0 = lane*16;
    float zv[16];
    #pragma unroll
    for (int i=0;i<16;i++) zv[i] = zb[(size_t)(t0+i)*DENC];
    float A = 1.f, Bv = 0.f;
    #pragma unroll
    for (int i=0;i<16;i++){
        int t = t0 + i;
        float pc = sp[t];
        float a  = (t==0) ? 0.f : (1.f - pc);
        float bb = (t==0) ? zv[i] : pc*zv[i];
        A = a*A;
        Bv = a*Bv + bb;
    }
    #pragma unroll
    for (int off=1; off<64; off<<=1){
        float Ap = __shfl_up(A, off);
        float Bp = __shfl_up(Bv, off);
        if (lane >= off){ Bv = A*Bp + Bv; A = A*Ap; }
    }
    float sin_ = __shfl_up(Bv, 1);
    if (lane == 0) sin_ = 0.f;
    float s = sin_;
    float* ob = zbar + ((size_t)b*L_)*DENC + d;
    #pragma unroll
    for (int i=0;i<16;i++){
        int t = t0 + i;
        float pc = sp[t];
        float a  = (t==0) ? 0.f : (1.f - pc);
        float bb = (t==0) ? zv[i] : pc*zv[i];
        s = a*s + bb;
        ob[(size_t)t*DENC] = s;
    }
}

__global__ void k_combine(float* __restrict__ x, const float* __restrict__ zbar, const int* __restrict__ cidx){
    int i = blockIdx.x*256 + threadIdx.x;
    int row = i >> 7, d = i & 127;
    int b = row >> 10;
    int ci = cidx[row];
    x[i] += zbar[((size_t)b*L_ + ci)*DENC + d];
}

__global__ void k_loss(const float* __restrict__ acc, void* __restrict__ out, const int* __restrict__ flag){
    float G = acc[0] / (float)BL;
    float F = acc[1] / (float)BL;
    float ratio = 1.2f*(5.0f*F*G + (1.0f-F)*(1.0f-G));
    if (flag[0]) ((bf16*)out)[(size_t)BL*VOCAB] = __float2bfloat16(ratio);
    else         ((float*)out)[(size_t)BL*VOCAB] = ratio;
}

// =========================================================================
extern "C" void kernel_launch(void* const* d_in, const int* in_sizes, int n_in,
                              void* d_out, int out_size, void* d_ws, size_t ws_size,
                              hipStream_t stream) {
    (void)out_size; (void)ws_size;
    const int* byte_ids = (const int*)d_in[0];

    float* ws = (float*)d_ws;
    size_t off = 0;
    int* FLAG = (int*)ws; off += 16;
    float* W32 = ws + off;

    k_detect<<<1, 64, 0, stream>>>(d_in[1], FLAG);

    CvtArgs ca;
    const float* w32[32];
    unsigned woff = 0;
    for (int i = 1; i < n_in && i < 32; i++){
        w32[i] = W32 + woff;
        ca.src[i-1] = d_in[i];
        ca.offs[i-1] = woff;
        woff += (unsigned)in_sizes[i];
    }
    ca.offs[31] = woff;
    off += woff;
    f16* W16h = (f16*)(ws + off); off += (woff+1)/2;
    const f16* w16[32];
    for (int i = 1; i < n_in && i < 32; i++) w16[i] = W16h + ca.offs[i-1];
    // f32 master needed only for: embed(1), wq(2), wk(3), norms(6,7), LN params (8,9,12,13,16,17,20,21,24,25,28,29)
    // slot j = idx-1 -> mask bits {0,1,2,5,6,7,8,11,12,15,16,19,20,23,24,27,28} = 0x199999E7
    k_cvt_all<<<2048, 256, 0, stream>>>(ca, W32, W16h, (int)woff, FLAG, 0x199999E7u);

    const float* embed    = w32[1];
    const float* wq       = w32[2];
    const float* wk       = w32[3];
    const float* norm_w   = w32[6];
    const float* norm_b   = w32[7];

    float* X    = ws + off; off += (size_t)BL*DENC;
    float* QKVf = ws + off; off += (size_t)BL*3*DMAIN;
    float* ATTf = ws + off; off += (size_t)BL*DMAIN;
    float* Hf   = ws + off; off += (size_t)BL*2*DMAIN;
    float* LNf  = ws + off; off += (size_t)BL*DMAIN;
    float* Z    = ws + off; off += (size_t)BL*DMAIN;
    float* COMPf= ws + off; off += (size_t)BL*DENC;
    float* P    = ws + off; off += BL;
    float* BH   = ws + off; off += BL;
    float* PCOMP= ws + off; off += BL;
    float* ACC  = ws + off; off += 8;
    int* CIDX   = (int*)(ws + off); off += BL;
    int* SRC    = (int*)(ws + off); off += BL;
    int* COUNTS = (int*)(ws + off); off += 64;

    f16* QKV16 = (f16*)QKVf;
    f16* ATT16 = (f16*)ATTf;
    f16* H16   = (f16*)Hf;
    f16* LN16  = (f16*)LNf;
    f16* COMP16= (f16*)COMPf;
    float* Qr  = ATTf;
    float* Kr  = Hf;
    float* ZDN = QKVf;
    float* ZBAR= QKVf + (size_t)BL*DENC;

    auto hgemm = [&](int K, const f16* A, const f16* W, const float* R, float* C, f16* C16,
                     void* Ob, int N, int mode, f16* Qd, f16* Kd, f16* Vd, int dS, int dhS){
        dim3 g((N+63)/64, BL/64);
        if (K == 128)      k_hgemm<128><<<g,256,0,stream>>>(A, W, R, C, C16, Ob, FLAG, N, mode, Qd, Kd, Vd, dS, dhS);
        else if (K == 256) k_hgemm<256><<<g,256,0,stream>>>(A, W, R, C, C16, Ob, FLAG, N, mode, Qd, Kd, Vd, dS, dhS);
        else               k_hgemm<512><<<g,256,0,stream>>>(A, W, R, C, C16, Ob, FLAG, N, mode, Qd, Kd, Vd, dS, dhS);
    };

    auto block128 = [&](float* Xs, const float* l1w, const float* l1b, const f16* qkvw, const f16* wo,
                        const float* l2w, const float* l2b, const f16* w1, const f16* w2){
        k_ln16<128><<<BL/4,256,0,stream>>>(Xs, l1w, l1b, LN16);
        hgemm(128, LN16, qkvw, nullptr, nullptr, nullptr, nullptr, 3*DENC, 5,
              QKV16, QKV16 + (size_t)BL*DENC, QKV16 + (size_t)2*BL*DENC, 7, 5);
        k_mflash<32><<<dim3(B_*NHEADS,16),256,0,stream>>>(QKV16, QKV16 + (size_t)BL*DENC,
                                                          QKV16 + (size_t)2*BL*DENC,
                                                          ATT16, nullptr, 0.17677669529663687f);
        hgemm(128, ATT16, wo, Xs, Xs, nullptr, nullptr, DENC, 1, nullptr, nullptr, nullptr, 0, 0);
        k_ln16<128><<<BL/4,256,0,stream>>>(Xs, l2w, l2b, LN16);
        hgemm(128, LN16, w1, nullptr, nullptr, H16, nullptr, 2*DENC, 2, nullptr, nullptr, nullptr, 0, 0);
        hgemm(256, H16, w2, Xs, Xs, nullptr, nullptr, DENC, 1, nullptr, nullptr, nullptr, 0, 0);
    };
    auto block_main = [&](float* Xs, const float* l1w, const float* l1b, const f16* qkvw, const f16* wo,
                          const float* l2w, const float* l2b, const f16* w1, const f16* w2){
        k_ln16<256><<<BL/4,256,0,stream>>>(Xs, l1w, l1b, LN16);
        hgemm(256, LN16, qkvw, nullptr, nullptr, nullptr, nullptr, 3*DMAIN, 5,
              QKV16, QKV16 + (size_t)BL*DMAIN, QKV16 + (size_t)2*BL*DMAIN, 8, 6);
        k_mflash<64><<<dim3(B_*NHEADS,16),256,0,stream>>>(QKV16, QKV16 + (size_t)BL*DMAIN,
                                                          QKV16 + (size_t)2*BL*DMAIN,
                                                          ATT16, COUNTS, 0.125f);
        hgemm(256, ATT16, wo, Xs, Xs, nullptr, nullptr, DMAIN, 1, nullptr, nullptr, nullptr, 0, 0);
        k_ln16<256><<<BL/4,256,0,stream>>>(Xs, l2w, l2b, LN16);
        hgemm(256, LN16, w1, nullptr, nullptr, H16, nullptr, 2*DMAIN, 2, nullptr, nullptr, nullptr, 0, 0);
        hgemm(512, H16, w2, Xs, Xs, nullptr, nullptr, DMAIN, 1, nullptr, nullptr, nullptr, 0, 0);
    };

    // ---- embed + encoder ----
    k_embed<<<BL*DENC/256, 256, 0, stream>>>(byte_ids, embed, X);
    for (int i = 0; i < 3; i++)
        block128(X, w32[8] + i*DENC, w32[9] + i*DENC, w16[10] + (size_t)i*3*DENC*DENC,
                 w16[11] + (size_t)i*DENC*DENC, w32[12] + i*DENC, w32[13] + i*DENC,
                 w16[14] + (size_t)i*2*DENC*DENC, w16[15] + (size_t)i*2*DENC*DENC);

    // ---- routing (f32) ----
    k_gemm2<<<dim3(4, BL/64), 256, 0, stream>>>(X, wq, wk, Qr, Kr, DENC);
    k_router<<<BL, 64, 0, stream>>>(Qr, Kr, P, BH, ACC);
    k_seq<<<B_, 64, 0, stream>>>(BH, P, CIDX, SRC, COUNTS, ACC);
    k_scatter2<<<BL, 128, 0, stream>>>(X, P, SRC, COUNTS, COMP16, PCOMP);

    // ---- main stack on compressed ----
    hgemm(128, COMP16, w16[4], nullptr, Z, nullptr, nullptr, DMAIN, 0, nullptr, nullptr, nullptr, 0, 0);
    for (int i = 0; i < 6; i++)
        block_main(Z, w32[16] + i*DMAIN, w32[17] + i*DMAIN, w16[18] + (size_t)i*3*DMAIN*DMAIN,
                   w16[19] + (size_t)i*DMAIN*DMAIN, w32[20] + i*DMAIN, w32[21] + i*DMAIN,
                   w16[22] + (size_t)i*2*DMAIN*DMAIN, w16[23] + (size_t)i*2*DMAIN*DMAIN);
    k_lngemm<256><<<dim3(2, BL/64), 256, 0, stream>>>(Z, w16[5], nullptr, nullptr, 0,
                                                      ZDN, nullptr, FLAG, DENC, 0);   // proj_dn

    // ---- EMA + dechunk combine ----
    k_ema2<<<256, 256, 0, stream>>>(ZDN, PCOMP, ZBAR);
    k_combine<<<BL*DENC/256, 256, 0, stream>>>(X, ZBAR, CIDX);

    // ---- decoder ----
    for (int i = 0; i < 3; i++)
        block128(X, w32[24] + i*DENC, w32[25] + i*DENC, w16[26] + (size_t)i*3*DENC*DENC,
                 w16[27] + (size_t)i*DENC*DENC, w32[28] + i*DENC, w32[29] + i*DENC,
                 w16[30] + (size_t)i*2*DENC*DENC, w16[31] + (size_t)i*2*DENC*DENC);

    // ---- final LN + tied head + loss ----
    k_lngemm<128><<<dim3(5, BL/64), 256, 0, stream>>>(X, w16[1], norm_w, norm_b, 1,
                                                      nullptr, d_out, FLAG, VOCAB, 3);
    k_loss<<<1,1,0,stream>>>(ACC, d_out, FLAG);
}

// Round 12
// 1242.017 us; speedup vs baseline: 1.0500x; 1.0125x over previous
//
#include <hip/hip_runtime.h>
#include <hip/hip_bf16.h>

#define B_ 8
#define L_ 1024
#define BL (B_*L_)
#define DENC 128
#define DMAIN 256
#define VOCAB 260
#define NHEADS 4

typedef __hip_bfloat16 bf16;
typedef _Float16 f16;
typedef f16 half8 __attribute__((ext_vector_type(8)));
typedef f16 half4 __attribute__((ext_vector_type(4)));
typedef f16 half2v __attribute__((ext_vector_type(2)));
typedef float f32x4 __attribute__((ext_vector_type(4)));

// ---------------- dtype detector ----------------
__global__ __launch_bounds__(64) void k_detect(const void* __restrict__ emb, int* __restrict__ flag){
    int lane = threadIdx.x;
    const unsigned short* u = (const unsigned short*)emb;
    int bad = 0;
    #pragma unroll
    for (int j = 0; j < 4; j++){
        unsigned short h = u[lane + 64*j];
        bf16 t = *(const bf16*)&h;
        float v = __bfloat162float(t);
        if (!(fabsf(v) < 1e4f)) bad++;
    }
    #pragma unroll
    for (int o = 32; o >= 1; o >>= 1) bad += __shfl_xor(bad, o);
    if (lane == 0) flag[0] = (bad == 0) ? 1 : 0;
}

// ---------------- fused convert: f16 copy always; f32 master only where needed ----------------
struct CvtArgs {
    const void* src[31];
    unsigned offs[32];
};
__global__ void k_cvt_all(CvtArgs a, float* __restrict__ dst, f16* __restrict__ dst16,
                          int total, const int* __restrict__ flag, unsigned f32mask){
    int isbf = flag[0];
    for (int i = blockIdx.x*256 + threadIdx.x; i < total; i += gridDim.x*256){
        int lo = 0, hi = 30;
        while (lo < hi){ int mid = (lo+hi+1)>>1; if (a.offs[mid] <= (unsigned)i) lo = mid; else hi = mid-1; }
        int j = i - (int)a.offs[lo];
        float v = isbf ? __bfloat162float(((const bf16*)a.src[lo])[j])
                       : ((const float*)a.src[lo])[j];
        if ((f32mask >> lo) & 1u) dst[i] = v;
        dst16[i] = (f16)v;
    }
}

// ---------------- embed gather ----------------
__global__ void k_embed(const int* __restrict__ ids, const float* __restrict__ emb, float* __restrict__ x){
    int i = blockIdx.x*256 + threadIdx.x;
    int row = i >> 7, d = i & 127;
    x[i] = emb[ids[row]*DENC + d];
}

// ---------------- layernorm: f32 in -> f16 out, 4 rows/block ----------------
template<int D>
__global__ __launch_bounds__(256) void k_ln16(const float* __restrict__ x, const float* __restrict__ w,
                                              const float* __restrict__ b, f16* __restrict__ y){
    int row = blockIdx.x*4 + (threadIdx.x >> 6);
    int lane = threadIdx.x & 63;
    const float* xr = x + (size_t)row*D;
    float v[D/64];
    float s = 0.f;
    #pragma unroll
    for (int j=0;j<D/64;j++){ v[j] = xr[lane + j*64]; s += v[j]; }
    #pragma unroll
    for (int o=32;o>=1;o>>=1) s += __shfl_xor(s,o);
    float mu = s / (float)D;
    float s2 = 0.f;
    #pragma unroll
    for (int j=0;j<D/64;j++){ float dd = v[j]-mu; s2 += dd*dd; }
    #pragma unroll
    for (int o=32;o>=1;o>>=1) s2 += __shfl_xor(s2,o);
    float inv = rsqrtf(s2/(float)D + 1e-5f);
    f16* yr = y + (size_t)row*D;
    #pragma unroll
    for (int j=0;j<D/64;j++){
        int d = lane + j*64;
        yr[d] = (f16)((v[j]-mu)*inv*w[d] + b[d]);
    }
}

// ---------------- f32 vector GEMM: fused wq/wk (router only) ----------------
#define GBM 64
#define GBN 64
#define GBK 32
__global__ __launch_bounds__(256) void k_gemm2(const float* __restrict__ A, const float* __restrict__ Wq,
        const float* __restrict__ Wk, float* __restrict__ Cq, float* __restrict__ Ck, int K)
{
    __shared__ float As[GBK][GBM+4];
    __shared__ float Ws[GBK][GBN+4];
    int tid = threadIdx.x;
    int bm = blockIdx.y * GBM;
    int bn = blockIdx.x * GBN;
    int tx = tid & 15, ty = tid >> 4;
    float acc[4][4] = {};
    for (int k0 = 0; k0 < K; k0 += GBK){
        #pragma unroll
        for (int i = tid; i < GBM*GBK; i += 256){
            int m = i >> 5, kk = i & 31;
            As[kk][m] = A[(size_t)(bm+m)*K + k0 + kk];
        }
        #pragma unroll
        for (int i = tid; i < GBN*GBK; i += 256){
            int n = i >> 5, kk = i & 31;
            int gn = bn + n;
            const float* W = (gn < 128) ? Wq : Wk;
            int wr = gn & 127;
            Ws[kk][n] = W[(size_t)wr*K + k0 + kk];
        }
        __syncthreads();
        #pragma unroll
        for (int kk = 0; kk < GBK; kk++){
            float a0[4], w0[4];
            *(float4*)a0 = *(const float4*)&As[kk][ty*4];
            *(float4*)w0 = *(const float4*)&Ws[kk][tx*4];
            #pragma unroll
            for (int i=0;i<4;i++)
                #pragma unroll
                for (int j=0;j<4;j++) acc[i][j] += a0[i]*w0[j];
        }
        __syncthreads();
    }
    #pragma unroll
    for (int i=0;i<4;i++){
        int m = bm + ty*4 + i;
        #pragma unroll
        for (int j=0;j<4;j++){
            int n = bn + tx*4 + j;
            float* C = (n < 128) ? Cq : Ck;
            C[(size_t)m*128 + (n & 127)] = acc[i][j];
        }
    }
}

// ---------------- f16 MFMA GEMM (R9-best: BK=32, [chunk][row] LDS), 64x64 tile ----------------
// modes: 0 C f32, 1 C = R + A@W^T, 2 gelu->C16 f16, 3 out-store, 5 split-head QKV f16 (V^T)
template<int K>
__global__ __launch_bounds__(256) void k_hgemm(const f16* __restrict__ A, const f16* __restrict__ W,
        const float* __restrict__ R, float* __restrict__ C, f16* __restrict__ C16,
        void* __restrict__ OutRaw, const int* __restrict__ flag, int N, int mode,
        f16* __restrict__ Qd, f16* __restrict__ Kd, f16* __restrict__ Vd,
        int dShift, int dhShift)
{
    __shared__ half8 As[4][64];
    __shared__ half8 Ws[4][64];
    int tid = threadIdx.x;
    int wave = tid >> 6, lane = tid & 63;
    int wr = wave >> 1, wc = wave & 1;
    int quad = lane >> 4, l15 = lane & 15;
    int bm = blockIdx.y * 64, bn = blockIdx.x * 64;

    f32x4 acc[2][2] = {};
    int srow = tid >> 2, sc8 = tid & 3;
    const f16* ap0 = A + (size_t)(bm + srow)*K + sc8*8;
    int gn = bn + srow;
    const f16* wp0 = W + (size_t)gn*K + sc8*8;
    bool wok = (gn < N);

    for (int k0 = 0; k0 < K; k0 += 32){
        __syncthreads();
        As[sc8][srow] = *(const half8*)(ap0 + k0);
        Ws[sc8][srow] = wok ? *(const half8*)(wp0 + k0) : (half8)(f16)0.f;
        __syncthreads();
        half8 af[2], wf[2];
        af[0] = As[quad][wr*32 + l15];
        af[1] = As[quad][wr*32 + 16 + l15];
        wf[0] = Ws[quad][wc*32 + l15];
        wf[1] = Ws[quad][wc*32 + 16 + l15];
        #pragma unroll
        for (int i=0;i<2;i++)
            #pragma unroll
            for (int j=0;j<2;j++)
                acc[i][j] = __builtin_amdgcn_mfma_f32_16x16x32_f16(af[i], wf[j], acc[i][j], 0, 0, 0);
    }

    #pragma unroll
    for (int j=0;j<2;j++){
        int n = bn + wc*32 + j*16 + l15;
        if (n >= N) continue;
        #pragma unroll
        for (int i=0;i<2;i++){
            #pragma unroll
            for (int r=0;r<4;r++){
                int m = bm + wr*32 + i*16 + quad*4 + r;
                float v = acc[i][j][r];
                if (mode == 5){
                    int which = n >> dShift;
                    int rem = n & ((1<<dShift)-1);
                    int hh = rem >> dhShift;
                    int dd = rem & ((1<<dhShift)-1);
                    int bb = m >> 10, tt = m & 1023;
                    int Hn = 1 << (dShift - dhShift);
                    f16* dst = (which==0) ? Qd : ((which==1) ? Kd : Vd);
                    if (which == 2)
                        dst[((((size_t)bb*Hn + hh) << dhShift) + dd)*L_ + tt] = (f16)v;  // V^T
                    else
                        dst[((((size_t)bb*Hn + hh)*L_ + tt) << dhShift) + dd] = (f16)v;
                    continue;
                }
                size_t off = (size_t)m*N + n;
                if (mode == 1){ C[off] = v + R[off]; }
                else if (mode == 2){
                    v = 0.5f*v*(1.0f + erff(v*0.70710678118654752f));
                    C16[off] = (f16)v;
                } else if (mode == 3){
                    if (flag[0]) ((bf16*)OutRaw)[off] = __float2bfloat16(v);
                    else         ((float*)OutRaw)[off] = v;
                } else C[off] = v;
            }
        }
    }
}

// ---------------- fused LN + f16 GEMM (proj_dn / head only, low N) ----------------
template<int K>
__global__ __launch_bounds__(256) void k_lngemm(const float* __restrict__ A, const f16* __restrict__ W,
        const float* __restrict__ lnw, const float* __restrict__ lnb, int doLN,
        float* __restrict__ C, void* __restrict__ OutRaw,
        const int* __restrict__ flag, int N, int mode)
{
    constexpr int SA = K + 8;
    constexpr int RPT = K/64;
    __shared__ f16 sA[64*SA];
    int tid = threadIdx.x;
    int wave = tid >> 6, lane = tid & 63;
    int wr = wave >> 1, wc = wave & 1;
    int quad = lane >> 4, l15 = lane & 15;
    int bm = blockIdx.y * 64, bn = blockIdx.x * 64;

    float wv_[RPT], bv_[RPT];
    #pragma unroll
    for (int j=0;j<RPT;j++){
        int d = lane*RPT + j;
        wv_[j] = doLN ? lnw[d] : 1.f;
        bv_[j] = doLN ? lnb[d] : 0.f;
    }
    for (int rr=0; rr<16; rr++){
        int row = wave*16 + rr;
        const float* xr = A + (size_t)(bm+row)*K + lane*RPT;
        float v[RPT];
        if (RPT==2){ float2 t = *(const float2*)xr; v[0]=t.x; v[1]=t.y; }
        else       { float4 t = *(const float4*)xr; v[0]=t.x; v[1]=t.y; v[2]=t.z; v[3]=t.w; }
        float mu = 0.f, inv = 1.f;
        if (doLN){
            float s=0.f;
            #pragma unroll
            for (int j=0;j<RPT;j++) s += v[j];
            #pragma unroll
            for (int o=32;o>=1;o>>=1) s += __shfl_xor(s,o);
            mu = s / (float)K;
            float s2=0.f;
            #pragma unroll
            for (int j=0;j<RPT;j++){ float dd=v[j]-mu; s2+=dd*dd; }
            #pragma unroll
            for (int o=32;o>=1;o>>=1) s2 += __shfl_xor(s2,o);
            inv = rsqrtf(s2/(float)K + 1e-5f);
        }
        if (RPT==2){
            half2v h;
            h[0]=(f16)((v[0]-mu)*inv*wv_[0]+bv_[0]);
            h[1]=(f16)((v[1]-mu)*inv*wv_[1]+bv_[1]);
            *(half2v*)&sA[row*SA + lane*2] = h;
        } else {
            half4 h;
            #pragma unroll
            for (int j=0;j<4;j++) h[j]=(f16)((v[j]-mu)*inv*wv_[j]+bv_[j]);
            *(half4*)&sA[row*SA + lane*4] = h;
        }
    }
    __syncthreads();

    f32x4 acc[2][2] = {};
    int n0 = bn + wc*32 + l15;
    bool ok0 = n0 < N, ok1 = (n0+16) < N;
    const f16* w0p = W + (size_t)n0*K + quad*8;
    const f16* w1p = W + (size_t)(n0+16)*K + quad*8;
    #pragma unroll 4
    for (int k0=0;k0<K;k0+=32){
        half8 af[2], wf[2];
        af[0] = *(const half8*)&sA[(wr*32 + l15)*SA + k0 + quad*8];
        af[1] = *(const half8*)&sA[(wr*32 + 16 + l15)*SA + k0 + quad*8];
        wf[0] = ok0 ? *(const half8*)(w0p + k0) : (half8)(f16)0.f;
        wf[1] = ok1 ? *(const half8*)(w1p + k0) : (half8)(f16)0.f;
        #pragma unroll
        for (int i=0;i<2;i++)
            #pragma unroll
            for (int j=0;j<2;j++)
                acc[i][j] = __builtin_amdgcn_mfma_f32_16x16x32_f16(af[i], wf[j], acc[i][j], 0, 0, 0);
    }

    #pragma unroll
    for (int j=0;j<2;j++){
        int n = bn + wc*32 + j*16 + l15;
        if (n >= N) continue;
        #pragma unroll
        for (int i=0;i<2;i++){
            #pragma unroll
            for (int r=0;r<4;r++){
                int m = bm + wr*32 + i*16 + quad*4 + r;
                float v = acc[i][j][r];
                size_t off = (size_t)m*N + n;
                if (mode == 3){
                    if (flag[0]) ((bf16*)OutRaw)[off] = __float2bfloat16(v);
                    else         ((float*)OutRaw)[off] = v;
                } else C[off] = v;
            }
        }
    }
}

// ---------------- MFMA f16 flash, f16 output ----------------
template<int DH>
__global__ __launch_bounds__(256) void k_mflash(const f16* __restrict__ Qh, const f16* __restrict__ Kh,
        const f16* __restrict__ Vt, f16* __restrict__ out, const int* __restrict__ counts,
        float scale)
{
    constexpr int BQ = 64, BK = 64;
    constexpr int RS = DH + 8;
    constexpr int PS = BK + 8;
    __shared__ f16 sQ[BQ*RS];
    __shared__ f16 sK[BK*RS];
    __shared__ f16 sVt[DH*PS];
    __shared__ f16 sP[BQ*PS];

    int x = blockIdx.x, b = x >> 2, h = x & 3;
    int yy = blockIdx.y;
    int qt = (yy < 8) ? yy : 23 - yy;
    int q0 = qt * BQ;
    int tid = threadIdx.x;
    int wv = tid >> 6, lane = tid & 63;
    int quad = lane >> 4, l15 = lane & 15;

    const f16* Qb = Qh + (size_t)x*L_*DH;
    const f16* Kb = Kh + (size_t)x*L_*DH;
    const f16* Vb = Vt + (size_t)x*DH*L_;
    int kcap = counts ? counts[b] : L_;
    int klen = min(kcap, q0 + BQ);

    for (int i = tid; i < BQ*DH/8; i += 256){
        int r = (8*i)/DH, c = (8*i)%DH;
        *(half8*)&sQ[r*RS + c] = *(const half8*)&Qb[(size_t)(q0+r)*DH + c];
    }

    float m[4], l[4];
    #pragma unroll
    for (int r=0;r<4;r++){ m[r] = -1e30f; l[r] = 0.f; }
    f32x4 accO[DH/16] = {};

    for (int k0 = 0; k0 < klen; k0 += BK){
        __syncthreads();
        for (int i = tid; i < BK*DH/8; i += 256){
            int r = (8*i)/DH, c = (8*i)%DH;
            *(half8*)&sK[r*RS + c] = *(const half8*)&Kb[(size_t)(k0+r)*DH + c];
        }
        for (int i = tid; i < DH*BK/8; i += 256){
            int r = (8*i)/BK, c = (8*i)%BK;
            *(half8*)&sVt[r*PS + c] = *(const half8*)&Vb[(size_t)r*L_ + k0 + c];
        }
        __syncthreads();

        half8 af[DH/32];
        #pragma unroll
        for (int ds=0; ds<DH/32; ds++)
            af[ds] = *(const half8*)&sQ[(16*wv + l15)*RS + quad*8 + 32*ds];
        f32x4 accS[4] = {};
        #pragma unroll
        for (int t=0;t<4;t++){
            #pragma unroll
            for (int ds=0; ds<DH/32; ds++){
                half8 bf = *(const half8*)&sK[(16*t + l15)*RS + quad*8 + 32*ds];
                accS[t] = __builtin_amdgcn_mfma_f32_16x16x32_f16(af[ds], bf, accS[t], 0, 0, 0);
            }
        }

        #pragma unroll
        for (int r=0;r<4;r++){
            int qrow = q0 + 16*wv + quad*4 + r;
            float sv[4];
            #pragma unroll
            for (int t=0;t<4;t++){
                float v = accS[t][r]*scale;
                int kp = k0 + 16*t + l15;
                if (kp > qrow || kp >= kcap) v = -1e30f;
                sv[t] = v;
            }
            float rm = fmaxf(fmaxf(sv[0],sv[1]), fmaxf(sv[2],sv[3]));
            rm = fmaxf(rm, __shfl_xor(rm, 1));
            rm = fmaxf(rm, __shfl_xor(rm, 2));
            rm = fmaxf(rm, __shfl_xor(rm, 4));
            rm = fmaxf(rm, __shfl_xor(rm, 8));
            float mn = fmaxf(m[r], rm);
            float al = __expf(m[r] - mn);
            float p0 = __expf(sv[0]-mn), p1 = __expf(sv[1]-mn);
            float p2 = __expf(sv[2]-mn), p3 = __expf(sv[3]-mn);
            float rs = p0+p1+p2+p3;
            rs += __shfl_xor(rs, 1);
            rs += __shfl_xor(rs, 2);
            rs += __shfl_xor(rs, 4);
            rs += __shfl_xor(rs, 8);
            l[r] = l[r]*al + rs;
            m[r] = mn;
            #pragma unroll
            for (int dt=0; dt<DH/16; dt++) accO[dt][r] *= al;
            int prow = 16*wv + quad*4 + r;
            sP[prow*PS + 16*0 + l15] = (f16)p0;
            sP[prow*PS + 16*1 + l15] = (f16)p1;
            sP[prow*PS + 16*2 + l15] = (f16)p2;
            sP[prow*PS + 16*3 + l15] = (f16)p3;
        }

        half8 pf[2];
        #pragma unroll
        for (int ks=0; ks<2; ks++)
            pf[ks] = *(const half8*)&sP[(16*wv + l15)*PS + quad*8 + 32*ks];
        #pragma unroll
        for (int dt=0; dt<DH/16; dt++){
            #pragma unroll
            for (int ks=0; ks<2; ks++){
                half8 bv = *(const half8*)&sVt[(16*dt + l15)*PS + quad*8 + 32*ks];
                accO[dt] = __builtin_amdgcn_mfma_f32_16x16x32_f16(pf[ks], bv, accO[dt], 0, 0, 0);
            }
        }
    }

    #pragma unroll
    for (int r=0;r<4;r++){
        float inv = 1.0f / l[r];
        int qrow = q0 + 16*wv + quad*4 + r;
        #pragma unroll
        for (int dt=0; dt<DH/16; dt++){
            int d = 16*dt + l15;
            out[((size_t)b*L_ + qrow)*(NHEADS*DH) + h*DH + d] = (f16)(accO[dt][r]*inv);
        }
    }
}

// ---------------- router (also zeroes ACC from block 0) ----------------
__global__ __launch_bounds__(64) void k_router(const float* __restrict__ Q, const float* __restrict__ Kr,
        float* __restrict__ p, float* __restrict__ bh, float* __restrict__ acc)
{
    int idx = blockIdx.x;
    int t = idx & (L_-1);
    int lane = threadIdx.x;
    if (idx == 0 && lane < 8) acc[lane] = 0.f;
    float pv;
    if (t == 0){ pv = 1.0f; }
    else {
        const float* qr = Q  + (size_t)idx*DENC;
        const float* kr = Kr + (size_t)(idx-1)*DENC;
        float qq=0.f, kk=0.f, qk=0.f;
        #pragma unroll
        for (int j=0;j<2;j++){
            float qv = qr[lane + j*64], kv = kr[lane + j*64];
            qq += qv*qv; kk += kv*kv; qk += qv*kv;
        }
        #pragma unroll
        for (int o=32;o>=1;o>>=1){ qq += __shfl_xor(qq,o); kk += __shfl_xor(kk,o); qk += __shfl_xor(qk,o); }
        float cosv = qk / (fmaxf(sqrtf(qq),1e-12f)*fmaxf(sqrtf(kk),1e-12f));
        pv = 0.5f*(1.0f - cosv);
        pv = fminf(fmaxf(pv, 0.0f), 1.0f);
    }
    if (lane == 0){ p[idx] = pv; bh[idx] = (pv >= 0.5f) ? 1.0f : 0.0f; }
}

// ---------------- per-batch cumsum + slot map + fused p/bh global sums ----------------
__global__ __launch_bounds__(64) void k_seq(const float* __restrict__ bh, const float* __restrict__ p,
                      int* __restrict__ cidx, int* __restrict__ src, int* __restrict__ counts,
                      float* __restrict__ acc){
    int b = blockIdx.x;
    int lane = threadIdx.x;
    int base = b*L_ + lane*16;
    int h[16];
    int cnt = 0;
    float ps = 0.f;
    #pragma unroll
    for (int j=0;j<16;j++){ h[j] = bh[base+j] > 0.5f; cnt += h[j]; ps += p[base+j]; }
    int inc = cnt;
    #pragma unroll
    for (int o=1;o<64;o<<=1){ int nb = __shfl_up(inc, o); if (lane >= o) inc += nb; }
    int run = inc - cnt;
    #pragma unroll
    for (int j=0;j<16;j++){
        run += h[j];
        int ci = run - 1; if (ci < 0) ci = 0;
        cidx[base+j] = ci;
        if (h[j]) src[b*L_ + run-1] = lane*16 + j;
    }
    float cs = (float)cnt;
    #pragma unroll
    for (int o=32;o>=1;o>>=1){ ps += __shfl_xor(ps,o); cs += __shfl_xor(cs,o); }
    if (lane == 0){ atomicAdd(&acc[0], ps); atomicAdd(&acc[1], cs); }
    if (lane == 63) counts[b] = inc;
}

// ---------------- scatter-compress to f16 (zero-filled) ----------------
__global__ __launch_bounds__(128) void k_scatter2(const float* __restrict__ x, const float* __restrict__ p,
        const int* __restrict__ src, const int* __restrict__ counts,
        f16* __restrict__ comp, float* __restrict__ pcomp)
{
    int s = blockIdx.x & (L_-1), b = blockIdx.x >> 10, d = threadIdx.x;
    int cnt = counts[b];
    f16* crow = comp + ((size_t)b*L_ + s)*DENC;
    if (s < cnt){
        int t = src[b*L_ + s];
        crow[d] = (f16)x[((size_t)b*L_ + t)*DENC + d];
        if (d == 0) pcomp[b*L_ + s] = p[b*L_ + t];
    } else {
        crow[d] = (f16)0.f;
        if (d == 0) pcomp[b*L_ + s] = 0.f;
    }
}

// ---------------- chunk EMA: 3-phase wave scan ----------------
__global__ __launch_bounds__(256) void k_ema2(const float* __restrict__ z, const float* __restrict__ pcomp,
                                              float* __restrict__ zbar){
    __shared__ float sp[L_];
    int blk = blockIdx.x;
    int b = blk >> 5;
    int tid = threadIdx.x, wv = tid >> 6, lane = tid & 63;
    int d = ((blk & 31) << 2) + wv;
    for (int i = tid; i < L_; i += 256){
        float pc = pcomp[b*L_ + i];
        sp[i] = fminf(fmaxf(pc, 1e-4f), 1.0f - 1e-4f);
    }
    __syncthreads();
    const float* zb = z + ((size_t)b*L_)*DENC + d;
    int t0 = lane*16;
    float zv[16];
    #pragma unroll
    for (int i=0;i<16;i++) zv[i] = zb[(size_t)(t0+i)*DENC];
    float A = 1.f, Bv = 0.f;
    #pragma unroll
    for (int i=0;i<16;i++){
        int t = t0 + i;
        float pc = sp[t];
        float a  = (t==0) ? 0.f : (1.f - pc);
        float bb = (t==0) ? zv[i] : pc*zv[i];
        A = a*A;
        Bv = a*Bv + bb;
    }
    #pragma unroll
    for (int off=1; off<64; off<<=1){
        float Ap = __shfl_up(A, off);
        float Bp = __shfl_up(Bv, off);
        if (lane >= off){ Bv = A*Bp + Bv; A = A*Ap; }
    }
    float sin_ = __shfl_up(Bv, 1);
    if (lane == 0) sin_ = 0.f;
    float s = sin_;
    float* ob = zbar + ((size_t)b*L_)*DENC + d;
    #pragma unroll
    for (int i=0;i<16;i++){
        int t = t0 + i;
        float pc = sp[t];
        float a  = (t==0) ? 0.f : (1.f - pc);
        float bb = (t==0) ? zv[i] : pc*zv[i];
        s = a*s + bb;
        ob[(size_t)t*DENC] = s;
    }
}

__global__ void k_combine(float* __restrict__ x, const float* __restrict__ zbar, const int* __restrict__ cidx){
    int i = blockIdx.x*256 + threadIdx.x;
    int row = i >> 7, d = i & 127;
    int b = row >> 10;
    int ci = cidx[row];
    x[i] += zbar[((size_t)b*L_ + ci)*DENC + d];
}

__global__ void k_loss(const float* __restrict__ acc, void* __restrict__ out, const int* __restrict__ flag){
    float G = acc[0] / (float)BL;
    float F = acc[1] / (float)BL;
    float ratio = 1.2f*(5.0f*F*G + (1.0f-F)*(1.0f-G));
    if (flag[0]) ((bf16*)out)[(size_t)BL*VOCAB] = __float2bfloat16(ratio);
    else         ((float*)out)[(size_t)BL*VOCAB] = ratio;
}

// =========================================================================
extern "C" void kernel_launch(void* const* d_in, const int* in_sizes, int n_in,
                              void* d_out, int out_size, void* d_ws, size_t ws_size,
                              hipStream_t stream) {
    (void)out_size; (void)ws_size;
    const int* byte_ids = (const int*)d_in[0];

    float* ws = (float*)d_ws;
    size_t off = 0;
    int* FLAG = (int*)ws; off += 16;
    float* W32 = ws + off;

    k_detect<<<1, 64, 0, stream>>>(d_in[1], FLAG);

    CvtArgs ca;
    const float* w32[32];
    unsigned woff = 0;
    for (int i = 1; i < n_in && i < 32; i++){
        w32[i] = W32 + woff;
        ca.src[i-1] = d_in[i];
        ca.offs[i-1] = woff;
        woff += (unsigned)in_sizes[i];
    }
    ca.offs[31] = woff;
    off += woff;
    f16* W16h = (f16*)(ws + off); off += (woff+1)/2;
    const f16* w16[32];
    for (int i = 1; i < n_in && i < 32; i++) w16[i] = W16h + ca.offs[i-1];
    k_cvt_all<<<2048, 256, 0, stream>>>(ca, W32, W16h, (int)woff, FLAG, 0x199999E7u);

    const float* embed    = w32[1];
    const float* wq       = w32[2];
    const float* wk       = w32[3];
    const float* norm_w   = w32[6];
    const float* norm_b   = w32[7];

    float* X    = ws + off; off += (size_t)BL*DENC;
    float* QKVf = ws + off; off += (size_t)BL*3*DMAIN;
    float* ATTf = ws + off; off += (size_t)BL*DMAIN;
    float* Hf   = ws + off; off += (size_t)BL*2*DMAIN;
    float* LNf  = ws + off; off += (size_t)BL*DMAIN;
    float* Z    = ws + off; off += (size_t)BL*DMAIN;
    float* COMPf= ws + off; off += (size_t)BL*DENC;
    float* P    = ws + off; off += BL;
    float* BH   = ws + off; off += BL;
    float* PCOMP= ws + off; off += BL;
    float* ACC  = ws + off; off += 8;
    int* CIDX   = (int*)(ws + off); off += BL;
    int* SRC    = (int*)(ws + off); off += BL;
    int* COUNTS = (int*)(ws + off); off += 64;

    f16* QKV16 = (f16*)QKVf;
    f16* ATT16 = (f16*)ATTf;
    f16* H16   = (f16*)Hf;
    f16* LN16  = (f16*)LNf;
    f16* COMP16= (f16*)COMPf;
    float* Qr  = ATTf;
    float* Kr  = Hf;
    float* ZDN = QKVf;
    float* ZBAR= QKVf + (size_t)BL*DENC;

    auto hgemm = [&](int K, const f16* A, const f16* W, const float* R, float* C, f16* C16,
                     void* Ob, int N, int mode, f16* Qd, f16* Kd, f16* Vd, int dS, int dhS){
        dim3 g((N+63)/64, BL/64);
        if (K == 128)      k_hgemm<128><<<g,256,0,stream>>>(A, W, R, C, C16, Ob, FLAG, N, mode, Qd, Kd, Vd, dS, dhS);
        else if (K == 256) k_hgemm<256><<<g,256,0,stream>>>(A, W, R, C, C16, Ob, FLAG, N, mode, Qd, Kd, Vd, dS, dhS);
        else               k_hgemm<512><<<g,256,0,stream>>>(A, W, R, C, C16, Ob, FLAG, N, mode, Qd, Kd, Vd, dS, dhS);
    };

    auto block128 = [&](float* Xs, const float* l1w, const float* l1b, const f16* qkvw, const f16* wo,
                        const float* l2w, const float* l2b, const f16* w1, const f16* w2){
        k_ln16<128><<<BL/4,256,0,stream>>>(Xs, l1w, l1b, LN16);
        hgemm(128, LN16, qkvw, nullptr, nullptr, nullptr, nullptr, 3*DENC, 5,
              QKV16, QKV16 + (size_t)BL*DENC, QKV16 + (size_t)2*BL*DENC, 7, 5);
        k_mflash<32><<<dim3(B_*NHEADS,16),256,0,stream>>>(QKV16, QKV16 + (size_t)BL*DENC,
                                                          QKV16 + (size_t)2*BL*DENC,
                                                          ATT16, nullptr, 0.17677669529663687f);
        hgemm(128, ATT16, wo, Xs, Xs, nullptr, nullptr, DENC, 1, nullptr, nullptr, nullptr, 0, 0);
        k_ln16<128><<<BL/4,256,0,stream>>>(Xs, l2w, l2b, LN16);
        hgemm(128, LN16, w1, nullptr, nullptr, H16, nullptr, 2*DENC, 2, nullptr, nullptr, nullptr, 0, 0);
        hgemm(256, H16, w2, Xs, Xs, nullptr, nullptr, DENC, 1, nullptr, nullptr, nullptr, 0, 0);
    };
    auto block_main = [&](float* Xs, const float* l1w, const float* l1b, const f16* qkvw, const f16* wo,
                          const float* l2w, const float* l2b, const f16* w1, const f16* w2){
        k_ln16<256><<<BL/4,256,0,stream>>>(Xs, l1w, l1b, LN16);
        hgemm(256, LN16, qkvw, nullptr, nullptr, nullptr, nullptr, 3*DMAIN, 5,
              QKV16, QKV16 + (size_t)BL*DMAIN, QKV16 + (size_t)2*BL*DMAIN, 8, 6);
        k_mflash<64><<<dim3(B_*NHEADS,16),256,0,stream>>>(QKV16, QKV16 + (size_t)BL*DMAIN,
                                                          QKV16 + (size_t)2*BL*DMAIN,
                                                          ATT16, COUNTS, 0.125f);
        hgemm(256, ATT16, wo, Xs, Xs, nullptr, nullptr, DMAIN, 1, nullptr, nullptr, nullptr, 0, 0);
        k_ln16<256><<<BL/4,256,0,stream>>>(Xs, l2w, l2b, LN16);
        hgemm(256, LN16, w1, nullptr, nullptr, H16, nullptr, 2*DMAIN, 2, nullptr, nullptr, nullptr, 0, 0);
        hgemm(512, H16, w2, Xs, Xs, nullptr, nullptr, DMAIN, 1, nullptr, nullptr, nullptr, 0, 0);
    };

    // ---- embed + encoder ----
    k_embed<<<BL*DENC/256, 256, 0, stream>>>(byte_ids, embed, X);
    for (int i = 0; i < 3; i++)
        block128(X, w32[8] + i*DENC, w32[9] + i*DENC, w16[10] + (size_t)i*3*DENC*DENC,
                 w16[11] + (size_t)i*DENC*DENC, w32[12] + i*DENC, w32[13] + i*DENC,
                 w16[14] + (size_t)i*2*DENC*DENC, w16[15] + (size_t)i*2*DENC*DENC);

    // ---- routing (f32) ----
    k_gemm2<<<dim3(4, BL/64), 256, 0, stream>>>(X, wq, wk, Qr, Kr, DENC);
    k_router<<<BL, 64, 0, stream>>>(Qr, Kr, P, BH, ACC);
    k_seq<<<B_, 64, 0, stream>>>(BH, P, CIDX, SRC, COUNTS, ACC);
    k_scatter2<<<BL, 128, 0, stream>>>(X, P, SRC, COUNTS, COMP16, PCOMP);

    // ---- main stack on compressed ----
    hgemm(128, COMP16, w16[4], nullptr, Z, nullptr, nullptr, DMAIN, 0, nullptr, nullptr, nullptr, 0, 0);
    for (int i = 0; i < 6; i++)
        block_main(Z, w32[16] + i*DMAIN, w32[17] + i*DMAIN, w16[18] + (size_t)i*3*DMAIN*DMAIN,
                   w16[19] + (size_t)i*DMAIN*DMAIN, w32[20] + i*DMAIN, w32[21] + i*DMAIN,
                   w16[22] + (size_t)i*2*DMAIN*DMAIN, w16[23] + (size_t)i*2*DMAIN*DMAIN);
    k_lngemm<256><<<dim3(2, BL/64), 256, 0, stream>>>(Z, w16[5], nullptr, nullptr, 0,
                                                      ZDN, nullptr, FLAG, DENC, 0);   // proj_dn

    // ---- EMA + dechunk combine ----
    k_ema2<<<256, 256, 0, stream>>>(ZDN, PCOMP, ZBAR);
    k_combine<<<BL*DENC/256, 256, 0, stream>>>(X, ZBAR, CIDX);

    // ---- decoder ----
    for (int i = 0; i < 3; i++)
        block128(X, w32[24] + i*DENC, w32[25] + i*DENC, w16[26] + (size_t)i*3*DENC*DENC,
                 w16[27] + (size_t)i*DENC*DENC, w32[28] + i*DENC, w32[29] + i*DENC,
                 w16[30] + (size_t)i*2*DENC*DENC, w16[31] + (size_t)i*2*DENC*DENC);

    // ---- final LN + tied head + loss ----
    k_lngemm<128><<<dim3(5, BL/64), 256, 0, stream>>>(X, w16[1], norm_w, norm_b, 1,
                                                      nullptr, d_out, FLAG, VOCAB, 3);
    k_loss<<<1,1,0,stream>>>(ACC, d_out, FLAG);
}

// Round 13
// 1167.672 us; speedup vs baseline: 1.1168x; 1.0637x over previous
//
#include <hip/hip_runtime.h>
#include <hip/hip_bf16.h>

#define B_ 8
#define L_ 1024
#define BL (B_*L_)
#define DENC 128
#define DMAIN 256
#define VOCAB 260
#define NHEADS 4

typedef __hip_bfloat16 bf16;
typedef _Float16 f16;
typedef f16 half8 __attribute__((ext_vector_type(8)));
typedef f16 half4 __attribute__((ext_vector_type(4)));
typedef f16 half2v __attribute__((ext_vector_type(2)));
typedef float f32x4 __attribute__((ext_vector_type(4)));

// ---------------- dtype detector ----------------
__global__ __launch_bounds__(64) void k_detect(const void* __restrict__ emb, int* __restrict__ flag){
    int lane = threadIdx.x;
    const unsigned short* u = (const unsigned short*)emb;
    int bad = 0;
    #pragma unroll
    for (int j = 0; j < 4; j++){
        unsigned short h = u[lane + 64*j];
        bf16 t = *(const bf16*)&h;
        float v = __bfloat162float(t);
        if (!(fabsf(v) < 1e4f)) bad++;
    }
    #pragma unroll
    for (int o = 32; o >= 1; o >>= 1) bad += __shfl_xor(bad, o);
    if (lane == 0) flag[0] = (bad == 0) ? 1 : 0;
}

// ---------------- fused convert ----------------
struct CvtArgs {
    const void* src[31];
    unsigned offs[32];
};
__global__ void k_cvt_all(CvtArgs a, float* __restrict__ dst, f16* __restrict__ dst16,
                          int total, const int* __restrict__ flag, unsigned f32mask){
    int isbf = flag[0];
    for (int i = blockIdx.x*256 + threadIdx.x; i < total; i += gridDim.x*256){
        int lo = 0, hi = 30;
        while (lo < hi){ int mid = (lo+hi+1)>>1; if (a.offs[mid] <= (unsigned)i) lo = mid; else hi = mid-1; }
        int j = i - (int)a.offs[lo];
        float v = isbf ? __bfloat162float(((const bf16*)a.src[lo])[j])
                       : ((const float*)a.src[lo])[j];
        if ((f32mask >> lo) & 1u) dst[i] = v;
        dst16[i] = (f16)v;
    }
}

// ---------------- embed gather + LN (enc L0) ----------------
__global__ __launch_bounds__(256) void k_embed_ln(const int* __restrict__ ids, const float* __restrict__ emb,
        const float* __restrict__ lnw, const float* __restrict__ lnb,
        float* __restrict__ x, f16* __restrict__ y){
    int row = blockIdx.x*4 + (threadIdx.x >> 6);
    int lane = threadIdx.x & 63;
    int id = ids[row];
    float v0 = emb[(size_t)id*DENC + lane];
    float v1 = emb[(size_t)id*DENC + 64 + lane];
    x[(size_t)row*DENC + lane] = v0;
    x[(size_t)row*DENC + 64 + lane] = v1;
    float s = v0 + v1;
    #pragma unroll
    for (int o=32;o>=1;o>>=1) s += __shfl_xor(s,o);
    float mu = s / (float)DENC;
    float d0 = v0-mu, d1 = v1-mu;
    float s2 = d0*d0 + d1*d1;
    #pragma unroll
    for (int o=32;o>=1;o>>=1) s2 += __shfl_xor(s2,o);
    float inv = rsqrtf(s2/(float)DENC + 1e-5f);
    y[(size_t)row*DENC + lane]      = (f16)(d0*inv*lnw[lane] + lnb[lane]);
    y[(size_t)row*DENC + 64 + lane] = (f16)(d1*inv*lnw[64+lane] + lnb[64+lane]);
}

// ---------------- standalone LN (unused sizes kept minimal) ----------------
template<int D>
__global__ __launch_bounds__(256) void k_ln16(const float* __restrict__ x, const float* __restrict__ w,
                                              const float* __restrict__ b, f16* __restrict__ y){
    int row = blockIdx.x*4 + (threadIdx.x >> 6);
    int lane = threadIdx.x & 63;
    const float* xr = x + (size_t)row*D;
    float v[D/64];
    float s = 0.f;
    #pragma unroll
    for (int j=0;j<D/64;j++){ v[j] = xr[lane + j*64]; s += v[j]; }
    #pragma unroll
    for (int o=32;o>=1;o>>=1) s += __shfl_xor(s,o);
    float mu = s / (float)D;
    float s2 = 0.f;
    #pragma unroll
    for (int j=0;j<D/64;j++){ float dd = v[j]-mu; s2 += dd*dd; }
    #pragma unroll
    for (int o=32;o>=1;o>>=1) s2 += __shfl_xor(s2,o);
    float inv = rsqrtf(s2/(float)D + 1e-5f);
    f16* yr = y + (size_t)row*D;
    #pragma unroll
    for (int j=0;j<D/64;j++){
        int d = lane + j*64;
        yr[d] = (f16)((v[j]-mu)*inv*w[d] + b[d]);
    }
}

// ---------------- f32 vector GEMM: fused wq/wk (router only) ----------------
#define GBM 64
#define GBN 64
#define GBK 32
__global__ __launch_bounds__(256) void k_gemm2(const float* __restrict__ A, const float* __restrict__ Wq,
        const float* __restrict__ Wk, float* __restrict__ Cq, float* __restrict__ Ck, int K)
{
    __shared__ float As[GBK][GBM+4];
    __shared__ float Ws[GBK][GBN+4];
    int tid = threadIdx.x;
    int bm = blockIdx.y * GBM;
    int bn = blockIdx.x * GBN;
    int tx = tid & 15, ty = tid >> 4;
    float acc[4][4] = {};
    for (int k0 = 0; k0 < K; k0 += GBK){
        #pragma unroll
        for (int i = tid; i < GBM*GBK; i += 256){
            int m = i >> 5, kk = i & 31;
            As[kk][m] = A[(size_t)(bm+m)*K + k0 + kk];
        }
        #pragma unroll
        for (int i = tid; i < GBN*GBK; i += 256){
            int n = i >> 5, kk = i & 31;
            int gn = bn + n;
            const float* W = (gn < 128) ? Wq : Wk;
            int wr = gn & 127;
            Ws[kk][n] = W[(size_t)wr*K + k0 + kk];
        }
        __syncthreads();
        #pragma unroll
        for (int kk = 0; kk < GBK; kk++){
            float a0[4], w0[4];
            *(float4*)a0 = *(const float4*)&As[kk][ty*4];
            *(float4*)w0 = *(const float4*)&Ws[kk][tx*4];
            #pragma unroll
            for (int i=0;i<4;i++)
                #pragma unroll
                for (int j=0;j<4;j++) acc[i][j] += a0[i]*w0[j];
        }
        __syncthreads();
    }
    #pragma unroll
    for (int i=0;i<4;i++){
        int m = bm + ty*4 + i;
        #pragma unroll
        for (int j=0;j<4;j++){
            int n = bn + tx*4 + j;
            float* C = (n < 128) ? Cq : Ck;
            C[(size_t)m*128 + (n & 127)] = acc[i][j];
        }
    }
}

// ---------------- f16 MFMA GEMM (R9-best: BK=32, [chunk][row] LDS), 64x64 tile ----------------
// modes: 0 C f32, 1 C = R + A@W^T, 2 gelu->C16 f16, 3 out-store, 5 split-head QKV f16 (V^T)
template<int K>
__global__ __launch_bounds__(256) void k_hgemm(const f16* __restrict__ A, const f16* __restrict__ W,
        const float* __restrict__ R, float* __restrict__ C, f16* __restrict__ C16,
        void* __restrict__ OutRaw, const int* __restrict__ flag, int N, int mode,
        f16* __restrict__ Qd, f16* __restrict__ Kd, f16* __restrict__ Vd,
        int dShift, int dhShift)
{
    __shared__ half8 As[4][64];
    __shared__ half8 Ws[4][64];
    int tid = threadIdx.x;
    int wave = tid >> 6, lane = tid & 63;
    int wr = wave >> 1, wc = wave & 1;
    int quad = lane >> 4, l15 = lane & 15;
    int bm = blockIdx.y * 64, bn = blockIdx.x * 64;

    f32x4 acc[2][2] = {};
    int srow = tid >> 2, sc8 = tid & 3;
    const f16* ap0 = A + (size_t)(bm + srow)*K + sc8*8;
    int gn = bn + srow;
    const f16* wp0 = W + (size_t)gn*K + sc8*8;
    bool wok = (gn < N);

    for (int k0 = 0; k0 < K; k0 += 32){
        __syncthreads();
        As[sc8][srow] = *(const half8*)(ap0 + k0);
        Ws[sc8][srow] = wok ? *(const half8*)(wp0 + k0) : (half8)(f16)0.f;
        __syncthreads();
        half8 af[2], wf[2];
        af[0] = As[quad][wr*32 + l15];
        af[1] = As[quad][wr*32 + 16 + l15];
        wf[0] = Ws[quad][wc*32 + l15];
        wf[1] = Ws[quad][wc*32 + 16 + l15];
        #pragma unroll
        for (int i=0;i<2;i++)
            #pragma unroll
            for (int j=0;j<2;j++)
                acc[i][j] = __builtin_amdgcn_mfma_f32_16x16x32_f16(af[i], wf[j], acc[i][j], 0, 0, 0);
    }

    #pragma unroll
    for (int j=0;j<2;j++){
        int n = bn + wc*32 + j*16 + l15;
        if (n >= N) continue;
        #pragma unroll
        for (int i=0;i<2;i++){
            #pragma unroll
            for (int r=0;r<4;r++){
                int m = bm + wr*32 + i*16 + quad*4 + r;
                float v = acc[i][j][r];
                if (mode == 5){
                    int which = n >> dShift;
                    int rem = n & ((1<<dShift)-1);
                    int hh = rem >> dhShift;
                    int dd = rem & ((1<<dhShift)-1);
                    int bb = m >> 10, tt = m & 1023;
                    int Hn = 1 << (dShift - dhShift);
                    f16* dst = (which==0) ? Qd : ((which==1) ? Kd : Vd);
                    if (which == 2)
                        dst[((((size_t)bb*Hn + hh) << dhShift) + dd)*L_ + tt] = (f16)v;  // V^T
                    else
                        dst[((((size_t)bb*Hn + hh)*L_ + tt) << dhShift) + dd] = (f16)v;
                    continue;
                }
                size_t off = (size_t)m*N + n;
                if (mode == 1){ C[off] = v + R[off]; }
                else if (mode == 2){
                    v = 0.5f*v*(1.0f + erff(v*0.70710678118654752f));
                    C16[off] = (f16)v;
                } else if (mode == 3){
                    if (flag[0]) ((bf16*)OutRaw)[off] = __float2bfloat16(v);
                    else         ((float*)OutRaw)[off] = v;
                } else C[off] = v;
            }
        }
    }
}

// ---------------- GEMM + residual + full-row LN fused (BM=32, full N per block) ----------------
// X = (hasR ? R : 0) + A@W^T ; if doLN: Y16 = LN(X) with lnw/lnb
template<int K, int N>
__global__ __launch_bounds__(256) void k_gfl(const f16* __restrict__ A, const f16* __restrict__ W,
        const float* __restrict__ R, float* __restrict__ X, f16* __restrict__ Y,
        const float* __restrict__ lnw, const float* __restrict__ lnb, int doLN, int hasR)
{
    constexpr int NT2 = N/32;              // col-tiles per wave
    __shared__ half8 As[4][32];
    __shared__ half8 Ws[4][N];
    __shared__ float sred[2][2][32];
    int tid = threadIdx.x;
    int wave = tid >> 6, lane = tid & 63;
    int wr = wave >> 1, wc = wave & 1;
    int quad = lane >> 4, l15 = lane & 15;
    int bm = blockIdx.x * 32;

    f32x4 acc[NT2] = {};
    int srow = (tid & 127) >> 2, sch = tid & 3;
    const f16* ap0 = A + (size_t)(bm + srow)*K + sch*8;
    int s4 = tid >> 2;

    for (int k0 = 0; k0 < K; k0 += 32){
        __syncthreads();
        if (tid < 128) As[sch][srow] = *(const half8*)(ap0 + k0);
        #pragma unroll
        for (int s = 0; s < N/64; s++){
            int rr = s4 + s*64;
            Ws[sch][rr] = *(const half8*)(W + (size_t)rr*K + sch*8 + k0);
        }
        __syncthreads();
        half8 af = As[quad][wr*16 + l15];
        #pragma unroll
        for (int j=0;j<NT2;j++){
            half8 wf = Ws[quad][(wc*NT2 + j)*16 + l15];
            acc[j] = __builtin_amdgcn_mfma_f32_16x16x32_f16(af, wf, acc[j], 0, 0, 0);
        }
    }

    // epilogue: residual + write X (+ optional full-row LN)
    float v[NT2][4];
    #pragma unroll
    for (int r=0;r<4;r++){
        int row = bm + wr*16 + quad*4 + r;
        #pragma unroll
        for (int j=0;j<NT2;j++){
            int col = (wc*NT2 + j)*16 + l15;
            float rv = hasR ? R[(size_t)row*N + col] : 0.f;
            v[j][r] = acc[j][r] + rv;
            X[(size_t)row*N + col] = v[j][r];
        }
    }
    if (doLN){
        int lrow0 = wr*16 + quad*4;
        float mu[4], inv[4];
        #pragma unroll
        for (int r=0;r<4;r++){
            float s = 0.f;
            #pragma unroll
            for (int j=0;j<NT2;j++) s += v[j][r];
            s += __shfl_xor(s, 1); s += __shfl_xor(s, 2);
            s += __shfl_xor(s, 4); s += __shfl_xor(s, 8);
            if (l15 == 0) sred[0][wc][lrow0 + r] = s;
        }
        __syncthreads();
        #pragma unroll
        for (int r=0;r<4;r++)
            mu[r] = (sred[0][0][lrow0 + r] + sred[0][1][lrow0 + r]) / (float)N;
        #pragma unroll
        for (int r=0;r<4;r++){
            float s2 = 0.f;
            #pragma unroll
            for (int j=0;j<NT2;j++){ float dd = v[j][r] - mu[r]; s2 += dd*dd; }
            s2 += __shfl_xor(s2, 1); s2 += __shfl_xor(s2, 2);
            s2 += __shfl_xor(s2, 4); s2 += __shfl_xor(s2, 8);
            if (l15 == 0) sred[1][wc][lrow0 + r] = s2;
        }
        __syncthreads();
        #pragma unroll
        for (int r=0;r<4;r++)
            inv[r] = rsqrtf((sred[1][0][lrow0 + r] + sred[1][1][lrow0 + r]) / (float)N + 1e-5f);
        float wv_[NT2], bv_[NT2];
        #pragma unroll
        for (int j=0;j<NT2;j++){
            int col = (wc*NT2 + j)*16 + l15;
            wv_[j] = lnw[col];
            bv_[j] = lnb[col];
        }
        #pragma unroll
        for (int r=0;r<4;r++){
            int row = bm + wr*16 + quad*4 + r;
            #pragma unroll
            for (int j=0;j<NT2;j++){
                int col = (wc*NT2 + j)*16 + l15;
                Y[(size_t)row*N + col] = (f16)((v[j][r] - mu[r])*inv[r]*wv_[j] + bv_[j]);
            }
        }
    }
}

// ---------------- fused LN + f16 GEMM (proj_dn only) ----------------
template<int K>
__global__ __launch_bounds__(256) void k_lngemm(const float* __restrict__ A, const f16* __restrict__ W,
        const float* __restrict__ lnw, const float* __restrict__ lnb, int doLN,
        float* __restrict__ C, void* __restrict__ OutRaw,
        const int* __restrict__ flag, int N, int mode)
{
    constexpr int SA = K + 8;
    constexpr int RPT = K/64;
    __shared__ f16 sA[64*SA];
    int tid = threadIdx.x;
    int wave = tid >> 6, lane = tid & 63;
    int wr = wave >> 1, wc = wave & 1;
    int quad = lane >> 4, l15 = lane & 15;
    int bm = blockIdx.y * 64, bn = blockIdx.x * 64;

    float wv_[RPT], bv_[RPT];
    #pragma unroll
    for (int j=0;j<RPT;j++){
        int d = lane*RPT + j;
        wv_[j] = doLN ? lnw[d] : 1.f;
        bv_[j] = doLN ? lnb[d] : 0.f;
    }
    for (int rr=0; rr<16; rr++){
        int row = wave*16 + rr;
        const float* xr = A + (size_t)(bm+row)*K + lane*RPT;
        float v[RPT];
        if (RPT==2){ float2 t = *(const float2*)xr; v[0]=t.x; v[1]=t.y; }
        else       { float4 t = *(const float4*)xr; v[0]=t.x; v[1]=t.y; v[2]=t.z; v[3]=t.w; }
        float mu = 0.f, inv = 1.f;
        if (doLN){
            float s=0.f;
            #pragma unroll
            for (int j=0;j<RPT;j++) s += v[j];
            #pragma unroll
            for (int o=32;o>=1;o>>=1) s += __shfl_xor(s,o);
            mu = s / (float)K;
            float s2=0.f;
            #pragma unroll
            for (int j=0;j<RPT;j++){ float dd=v[j]-mu; s2+=dd*dd; }
            #pragma unroll
            for (int o=32;o>=1;o>>=1) s2 += __shfl_xor(s2,o);
            inv = rsqrtf(s2/(float)K + 1e-5f);
        }
        if (RPT==2){
            half2v h;
            h[0]=(f16)((v[0]-mu)*inv*wv_[0]+bv_[0]);
            h[1]=(f16)((v[1]-mu)*inv*wv_[1]+bv_[1]);
            *(half2v*)&sA[row*SA + lane*2] = h;
        } else {
            half4 h;
            #pragma unroll
            for (int j=0;j<4;j++) h[j]=(f16)((v[j]-mu)*inv*wv_[j]+bv_[j]);
            *(half4*)&sA[row*SA + lane*4] = h;
        }
    }
    __syncthreads();

    f32x4 acc[2][2] = {};
    int n0 = bn + wc*32 + l15;
    bool ok0 = n0 < N, ok1 = (n0+16) < N;
    const f16* w0p = W + (size_t)n0*K + quad*8;
    const f16* w1p = W + (size_t)(n0+16)*K + quad*8;
    #pragma unroll 4
    for (int k0=0;k0<K;k0+=32){
        half8 af[2], wf[2];
        af[0] = *(const half8*)&sA[(wr*32 + l15)*SA + k0 + quad*8];
        af[1] = *(const half8*)&sA[(wr*32 + 16 + l15)*SA + k0 + quad*8];
        wf[0] = ok0 ? *(const half8*)(w0p + k0) : (half8)(f16)0.f;
        wf[1] = ok1 ? *(const half8*)(w1p + k0) : (half8)(f16)0.f;
        #pragma unroll
        for (int i=0;i<2;i++)
            #pragma unroll
            for (int j=0;j<2;j++)
                acc[i][j] = __builtin_amdgcn_mfma_f32_16x16x32_f16(af[i], wf[j], acc[i][j], 0, 0, 0);
    }

    #pragma unroll
    for (int j=0;j<2;j++){
        int n = bn + wc*32 + j*16 + l15;
        if (n >= N) continue;
        #pragma unroll
        for (int i=0;i<2;i++){
            #pragma unroll
            for (int r=0;r<4;r++){
                int m = bm + wr*32 + i*16 + quad*4 + r;
                float v = acc[i][j][r];
                size_t off = (size_t)m*N + n;
                if (mode == 3){
                    if (flag[0]) ((bf16*)OutRaw)[off] = __float2bfloat16(v);
                    else         ((float*)OutRaw)[off] = v;
                } else C[off] = v;
            }
        }
    }
}

// ---------------- MFMA f16 flash, f16 output ----------------
template<int DH>
__global__ __launch_bounds__(256) void k_mflash(const f16* __restrict__ Qh, const f16* __restrict__ Kh,
        const f16* __restrict__ Vt, f16* __restrict__ out, const int* __restrict__ counts,
        float scale)
{
    constexpr int BQ = 64, BK = 64;
    constexpr int RS = DH + 8;
    constexpr int PS = BK + 8;
    __shared__ f16 sQ[BQ*RS];
    __shared__ f16 sK[BK*RS];
    __shared__ f16 sVt[DH*PS];
    __shared__ f16 sP[BQ*PS];

    int x = blockIdx.x, b = x >> 2, h = x & 3;
    int yy = blockIdx.y;
    int qt = (yy < 8) ? yy : 23 - yy;
    int q0 = qt * BQ;
    int tid = threadIdx.x;
    int wv = tid >> 6, lane = tid & 63;
    int quad = lane >> 4, l15 = lane & 15;

    const f16* Qb = Qh + (size_t)x*L_*DH;
    const f16* Kb = Kh + (size_t)x*L_*DH;
    const f16* Vb = Vt + (size_t)x*DH*L_;
    int kcap = counts ? counts[b] : L_;
    int klen = min(kcap, q0 + BQ);

    for (int i = tid; i < BQ*DH/8; i += 256){
        int r = (8*i)/DH, c = (8*i)%DH;
        *(half8*)&sQ[r*RS + c] = *(const half8*)&Qb[(size_t)(q0+r)*DH + c];
    }

    float m[4], l[4];
    #pragma unroll
    for (int r=0;r<4;r++){ m[r] = -1e30f; l[r] = 0.f; }
    f32x4 accO[DH/16] = {};

    for (int k0 = 0; k0 < klen; k0 += BK){
        __syncthreads();
        for (int i = tid; i < BK*DH/8; i += 256){
            int r = (8*i)/DH, c = (8*i)%DH;
            *(half8*)&sK[r*RS + c] = *(const half8*)&Kb[(size_t)(k0+r)*DH + c];
        }
        for (int i = tid; i < DH*BK/8; i += 256){
            int r = (8*i)/BK, c = (8*i)%BK;
            *(half8*)&sVt[r*PS + c] = *(const half8*)&Vb[(size_t)r*L_ + k0 + c];
        }
        __syncthreads();

        half8 af[DH/32];
        #pragma unroll
        for (int ds=0; ds<DH/32; ds++)
            af[ds] = *(const half8*)&sQ[(16*wv + l15)*RS + quad*8 + 32*ds];
        f32x4 accS[4] = {};
        #pragma unroll
        for (int t=0;t<4;t++){
            #pragma unroll
            for (int ds=0; ds<DH/32; ds++){
                half8 bf = *(const half8*)&sK[(16*t + l15)*RS + quad*8 + 32*ds];
                accS[t] = __builtin_amdgcn_mfma_f32_16x16x32_f16(af[ds], bf, accS[t], 0, 0, 0);
            }
        }

        #pragma unroll
        for (int r=0;r<4;r++){
            int qrow = q0 + 16*wv + quad*4 + r;
            float sv[4];
            #pragma unroll
            for (int t=0;t<4;t++){
                float v = accS[t][r]*scale;
                int kp = k0 + 16*t + l15;
                if (kp > qrow || kp >= kcap) v = -1e30f;
                sv[t] = v;
            }
            float rm = fmaxf(fmaxf(sv[0],sv[1]), fmaxf(sv[2],sv[3]));
            rm = fmaxf(rm, __shfl_xor(rm, 1));
            rm = fmaxf(rm, __shfl_xor(rm, 2));
            rm = fmaxf(rm, __shfl_xor(rm, 4));
            rm = fmaxf(rm, __shfl_xor(rm, 8));
            float mn = fmaxf(m[r], rm);
            float al = __expf(m[r] - mn);
            float p0 = __expf(sv[0]-mn), p1 = __expf(sv[1]-mn);
            float p2 = __expf(sv[2]-mn), p3 = __expf(sv[3]-mn);
            float rs = p0+p1+p2+p3;
            rs += __shfl_xor(rs, 1);
            rs += __shfl_xor(rs, 2);
            rs += __shfl_xor(rs, 4);
            rs += __shfl_xor(rs, 8);
            l[r] = l[r]*al + rs;
            m[r] = mn;
            #pragma unroll
            for (int dt=0; dt<DH/16; dt++) accO[dt][r] *= al;
            int prow = 16*wv + quad*4 + r;
            sP[prow*PS + 16*0 + l15] = (f16)p0;
            sP[prow*PS + 16*1 + l15] = (f16)p1;
            sP[prow*PS + 16*2 + l15] = (f16)p2;
            sP[prow*PS + 16*3 + l15] = (f16)p3;
        }

        half8 pf[2];
        #pragma unroll
        for (int ks=0; ks<2; ks++)
            pf[ks] = *(const half8*)&sP[(16*wv + l15)*PS + quad*8 + 32*ks];
        #pragma unroll
        for (int dt=0; dt<DH/16; dt++){
            #pragma unroll
            for (int ks=0; ks<2; ks++){
                half8 bv = *(const half8*)&sVt[(16*dt + l15)*PS + quad*8 + 32*ks];
                accO[dt] = __builtin_amdgcn_mfma_f32_16x16x32_f16(pf[ks], bv, accO[dt], 0, 0, 0);
            }
        }
    }

    #pragma unroll
    for (int r=0;r<4;r++){
        float inv = 1.0f / l[r];
        int qrow = q0 + 16*wv + quad*4 + r;
        #pragma unroll
        for (int dt=0; dt<DH/16; dt++){
            int d = 16*dt + l15;
            out[((size_t)b*L_ + qrow)*(NHEADS*DH) + h*DH + d] = (f16)(accO[dt][r]*inv);
        }
    }
}

// ---------------- router (also zeroes ACC) ----------------
__global__ __launch_bounds__(64) void k_router(const float* __restrict__ Q, const float* __restrict__ Kr,
        float* __restrict__ p, float* __restrict__ bh, float* __restrict__ acc)
{
    int idx = blockIdx.x;
    int t = idx & (L_-1);
    int lane = threadIdx.x;
    if (idx == 0 && lane < 8) acc[lane] = 0.f;
    float pv;
    if (t == 0){ pv = 1.0f; }
    else {
        const float* qr = Q  + (size_t)idx*DENC;
        const float* kr = Kr + (size_t)(idx-1)*DENC;
        float qq=0.f, kk=0.f, qk=0.f;
        #pragma unroll
        for (int j=0;j<2;j++){
            float qv = qr[lane + j*64], kv = kr[lane + j*64];
            qq += qv*qv; kk += kv*kv; qk += qv*kv;
        }
        #pragma unroll
        for (int o=32;o>=1;o>>=1){ qq += __shfl_xor(qq,o); kk += __shfl_xor(kk,o); qk += __shfl_xor(qk,o); }
        float cosv = qk / (fmaxf(sqrtf(qq),1e-12f)*fmaxf(sqrtf(kk),1e-12f));
        pv = 0.5f*(1.0f - cosv);
        pv = fminf(fmaxf(pv, 0.0f), 1.0f);
    }
    if (lane == 0){ p[idx] = pv; bh[idx] = (pv >= 0.5f) ? 1.0f : 0.0f; }
}

// ---------------- per-batch cumsum + slot map + fused p/bh sums ----------------
__global__ __launch_bounds__(64) void k_seq(const float* __restrict__ bh, const float* __restrict__ p,
                      int* __restrict__ cidx, int* __restrict__ src, int* __restrict__ counts,
                      float* __restrict__ acc){
    int b = blockIdx.x;
    int lane = threadIdx.x;
    int base = b*L_ + lane*16;
    int h[16];
    int cnt = 0;
    float ps = 0.f;
    #pragma unroll
    for (int j=0;j<16;j++){ h[j] = bh[base+j] > 0.5f; cnt += h[j]; ps += p[base+j]; }
    int inc = cnt;
    #pragma unroll
    for (int o=1;o<64;o<<=1){ int nb = __shfl_up(inc, o); if (lane >= o) inc += nb; }
    int run = inc - cnt;
    #pragma unroll
    for (int j=0;j<16;j++){
        run += h[j];
        int ci = run - 1; if (ci < 0) ci = 0;
        cidx[base+j] = ci;
        if (h[j]) src[b*L_ + run-1] = lane*16 + j;
    }
    float cs = (float)cnt;
    #pragma unroll
    for (int o=32;o>=1;o>>=1){ ps += __shfl_xor(ps,o); cs += __shfl_xor(cs,o); }
    if (lane == 0){ atomicAdd(&acc[0], ps); atomicAdd(&acc[1], cs); }
    if (lane == 63) counts[b] = inc;
}

// ---------------- scatter-compress to f16 (zero-filled) ----------------
__global__ __launch_bounds__(128) void k_scatter2(const float* __restrict__ x, const float* __restrict__ p,
        const int* __restrict__ src, const int* __restrict__ counts,
        f16* __restrict__ comp, float* __restrict__ pcomp)
{
    int s = blockIdx.x & (L_-1), b = blockIdx.x >> 10, d = threadIdx.x;
    int cnt = counts[b];
    f16* crow = comp + ((size_t)b*L_ + s)*DENC;
    if (s < cnt){
        int t = src[b*L_ + s];
        crow[d] = (f16)x[((size_t)b*L_ + t)*DENC + d];
        if (d == 0) pcomp[b*L_ + s] = p[b*L_ + t];
    } else {
        crow[d] = (f16)0.f;
        if (d == 0) pcomp[b*L_ + s] = 0.f;
    }
}

// ---------------- chunk EMA: 3-phase wave scan ----------------
__global__ __launch_bounds__(256) void k_ema2(const float* __restrict__ z, const float* __restrict__ pcomp,
                                              float* __restrict__ zbar){
    __shared__ float sp[L_];
    int blk = blockIdx.x;
    int b = blk >> 5;
    int tid = threadIdx.x, wv = tid >> 6, lane = tid & 63;
    int d = ((blk & 31) << 2) + wv;
    for (int i = tid; i < L_; i += 256){
        float pc = pcomp[b*L_ + i];
        sp[i] = fminf(fmaxf(pc, 1e-4f), 1.0f - 1e-4f);
    }
    __syncthreads();
    const float* zb = z + ((size_t)b*L_)*DENC + d;
    int t0 = lane*16;
    float zv[16];
    #pragma unroll
    for (int i=0;i<16;i++) zv[i] = zb[(size_t)(t0+i)*DENC];
    float A = 1.f, Bv = 0.f;
    #pragma unroll
    for (int i=0;i<16;i++){
        int t = t0 + i;
        float pc = sp[t];
        float a  = (t==0) ? 0.f : (1.f - pc);
        float bb = (t==0) ? zv[i] : pc*zv[i];
        A = a*A;
        Bv = a*Bv + bb;
    }
    #pragma unroll
    for (int off=1; off<64; off<<=1){
        float Ap = __shfl_up(A, off);
        float Bp = __shfl_up(Bv, off);
        if (lane >= off){ Bv = A*Bp + Bv; A = A*Ap; }
    }
    float sin_ = __shfl_up(Bv, 1);
    if (lane == 0) sin_ = 0.f;
    float s = sin_;
    float* ob = zbar + ((size_t)b*L_)*DENC + d;
    #pragma unroll
    for (int i=0;i<16;i++){
        int t = t0 + i;
        float pc = sp[t];
        float a  = (t==0) ? 0.f : (1.f - pc);
        float bb = (t==0) ? zv[i] : pc*zv[i];
        s = a*s + bb;
        ob[(size_t)t*DENC] = s;
    }
}

// ---------------- combine (x += zbar gather) + LN (dec L0) ----------------
__global__ __launch_bounds__(256) void k_combine_ln(float* __restrict__ x, const float* __restrict__ zbar,
        const int* __restrict__ cidx, const float* __restrict__ lnw, const float* __restrict__ lnb,
        f16* __restrict__ y){
    int row = blockIdx.x*4 + (threadIdx.x >> 6);
    int lane = threadIdx.x & 63;
    int b = row >> 10;
    int ci = cidx[row];
    const float* zr = zbar + ((size_t)b*L_ + ci)*DENC;
    float v0 = x[(size_t)row*DENC + lane]      + zr[lane];
    float v1 = x[(size_t)row*DENC + 64 + lane] + zr[64 + lane];
    x[(size_t)row*DENC + lane] = v0;
    x[(size_t)row*DENC + 64 + lane] = v1;
    float s = v0 + v1;
    #pragma unroll
    for (int o=32;o>=1;o>>=1) s += __shfl_xor(s,o);
    float mu = s / (float)DENC;
    float d0 = v0-mu, d1 = v1-mu;
    float s2 = d0*d0 + d1*d1;
    #pragma unroll
    for (int o=32;o>=1;o>>=1) s2 += __shfl_xor(s2,o);
    float inv = rsqrtf(s2/(float)DENC + 1e-5f);
    y[(size_t)row*DENC + lane]      = (f16)(d0*inv*lnw[lane] + lnb[lane]);
    y[(size_t)row*DENC + 64 + lane] = (f16)(d1*inv*lnw[64+lane] + lnb[64+lane]);
}

__global__ void k_loss(const float* __restrict__ acc, void* __restrict__ out, const int* __restrict__ flag){
    float G = acc[0] / (float)BL;
    float F = acc[1] / (float)BL;
    float ratio = 1.2f*(5.0f*F*G + (1.0f-F)*(1.0f-G));
    if (flag[0]) ((bf16*)out)[(size_t)BL*VOCAB] = __float2bfloat16(ratio);
    else         ((float*)out)[(size_t)BL*VOCAB] = ratio;
}

// =========================================================================
extern "C" void kernel_launch(void* const* d_in, const int* in_sizes, int n_in,
                              void* d_out, int out_size, void* d_ws, size_t ws_size,
                              hipStream_t stream) {
    (void)out_size; (void)ws_size;
    const int* byte_ids = (const int*)d_in[0];

    float* ws = (float*)d_ws;
    size_t off = 0;
    int* FLAG = (int*)ws; off += 16;
    float* W32 = ws + off;

    k_detect<<<1, 64, 0, stream>>>(d_in[1], FLAG);

    CvtArgs ca;
    const float* w32[32];
    unsigned woff = 0;
    for (int i = 1; i < n_in && i < 32; i++){
        w32[i] = W32 + woff;
        ca.src[i-1] = d_in[i];
        ca.offs[i-1] = woff;
        woff += (unsigned)in_sizes[i];
    }
    ca.offs[31] = woff;
    off += woff;
    f16* W16h = (f16*)(ws + off); off += (woff+1)/2;
    const f16* w16[32];
    for (int i = 1; i < n_in && i < 32; i++) w16[i] = W16h + ca.offs[i-1];
    k_cvt_all<<<2048, 256, 0, stream>>>(ca, W32, W16h, (int)woff, FLAG, 0x199999E7u);

    const float* embed    = w32[1];
    const float* wq       = w32[2];
    const float* wk       = w32[3];
    const float* norm_w   = w32[6];
    const float* norm_b   = w32[7];

    float* X    = ws + off; off += (size_t)BL*DENC;
    float* QKVf = ws + off; off += (size_t)BL*3*DMAIN;
    float* ATTf = ws + off; off += (size_t)BL*DMAIN;
    float* Hf   = ws + off; off += (size_t)BL*2*DMAIN;
    float* LNf  = ws + off; off += (size_t)BL*DMAIN;
    float* Z    = ws + off; off += (size_t)BL*DMAIN;
    float* COMPf= ws + off; off += (size_t)BL*DENC;
    float* P    = ws + off; off += BL;
    float* BH   = ws + off; off += BL;
    float* PCOMP= ws + off; off += BL;
    float* ACC  = ws + off; off += 8;
    int* CIDX   = (int*)(ws + off); off += BL;
    int* SRC    = (int*)(ws + off); off += BL;
    int* COUNTS = (int*)(ws + off); off += 64;

    f16* QKV16 = (f16*)QKVf;
    f16* ATT16 = (f16*)ATTf;
    f16* H16   = (f16*)Hf;
    f16* LN16  = (f16*)LNf;
    f16* COMP16= (f16*)COMPf;
    float* Qr  = ATTf;
    float* Kr  = Hf;
    float* ZDN = QKVf;
    float* ZBAR= QKVf + (size_t)BL*DENC;

    auto hgemm = [&](int K, const f16* A, const f16* W, const float* R, float* C, f16* C16,
                     void* Ob, int N, int mode, f16* Qd, f16* Kd, f16* Vd, int dS, int dhS){
        dim3 g((N+63)/64, BL/64);
        if (K == 128)      k_hgemm<128><<<g,256,0,stream>>>(A, W, R, C, C16, Ob, FLAG, N, mode, Qd, Kd, Vd, dS, dhS);
        else if (K == 256) k_hgemm<256><<<g,256,0,stream>>>(A, W, R, C, C16, Ob, FLAG, N, mode, Qd, Kd, Vd, dS, dhS);
        else               k_hgemm<512><<<g,256,0,stream>>>(A, W, R, C, C16, Ob, FLAG, N, mode, Qd, Kd, Vd, dS, dhS);
    };
    auto gfl = [&](int K, int N, const f16* A, const f16* W, const float* R, float* Xo, f16* Y,
                   const float* lw, const float* lb, int doLN, int hasR){
        dim3 g(BL/32);
        if (K == 128 && N == 128)      k_gfl<128,128><<<g,256,0,stream>>>(A, W, R, Xo, Y, lw, lb, doLN, hasR);
        else if (K == 256 && N == 128) k_gfl<256,128><<<g,256,0,stream>>>(A, W, R, Xo, Y, lw, lb, doLN, hasR);
        else if (K == 128 && N == 256) k_gfl<128,256><<<g,256,0,stream>>>(A, W, R, Xo, Y, lw, lb, doLN, hasR);
        else if (K == 256 && N == 256) k_gfl<256,256><<<g,256,0,stream>>>(A, W, R, Xo, Y, lw, lb, doLN, hasR);
        else                           k_gfl<512,256><<<g,256,0,stream>>>(A, W, R, Xo, Y, lw, lb, doLN, hasR);
    };

    // D=128 layer: assumes LN16 already holds LN1(x); writes LN16 for next stage
    auto block128 = [&](float* Xs, const f16* qkvw, const f16* wo,
                        const float* l2w, const float* l2b, const f16* w1, const f16* w2,
                        const float* nlw, const float* nlb, int doNext){
        hgemm(128, LN16, qkvw, nullptr, nullptr, nullptr, nullptr, 3*DENC, 5,
              QKV16, QKV16 + (size_t)BL*DENC, QKV16 + (size_t)2*BL*DENC, 7, 5);
        k_mflash<32><<<dim3(B_*NHEADS,16),256,0,stream>>>(QKV16, QKV16 + (size_t)BL*DENC,
                                                          QKV16 + (size_t)2*BL*DENC,
                                                          ATT16, nullptr, 0.17677669529663687f);
        gfl(128, 128, ATT16, wo, Xs, Xs, LN16, l2w, l2b, 1, 1);
        hgemm(128, LN16, w1, nullptr, nullptr, H16, nullptr, 2*DENC, 2, nullptr, nullptr, nullptr, 0, 0);
        gfl(256, 128, H16, w2, Xs, Xs, LN16, nlw, nlb, doNext, 1);
    };
    auto block_main = [&](float* Xs, const f16* qkvw, const f16* wo,
                          const float* l2w, const float* l2b, const f16* w1, const f16* w2,
                          const float* nlw, const float* nlb, int doNext){
        hgemm(256, LN16, qkvw, nullptr, nullptr, nullptr, nullptr, 3*DMAIN, 5,
              QKV16, QKV16 + (size_t)BL*DMAIN, QKV16 + (size_t)2*BL*DMAIN, 8, 6);
        k_mflash<64><<<dim3(B_*NHEADS,16),256,0,stream>>>(QKV16, QKV16 + (size_t)BL*DMAIN,
                                                          QKV16 + (size_t)2*BL*DMAIN,
                                                          ATT16, COUNTS, 0.125f);
        gfl(256, 256, ATT16, wo, Xs, Xs, LN16, l2w, l2b, 1, 1);
        hgemm(256, LN16, w1, nullptr, nullptr, H16, nullptr, 2*DMAIN, 2, nullptr, nullptr, nullptr, 0, 0);
        gfl(512, 256, H16, w2, Xs, Xs, LN16, nlw, nlb, doNext, 1);
    };

    // ---- embed + LN1(enc0) + encoder ----
    k_embed_ln<<<BL/4, 256, 0, stream>>>(byte_ids, embed, w32[8], w32[9], X, LN16);
    for (int i = 0; i < 3; i++)
        block128(X, w16[10] + (size_t)i*3*DENC*DENC, w16[11] + (size_t)i*DENC*DENC,
                 w32[12] + i*DENC, w32[13] + i*DENC,
                 w16[14] + (size_t)i*2*DENC*DENC, w16[15] + (size_t)i*2*DENC*DENC,
                 (i < 2) ? w32[8] + (i+1)*DENC : nullptr,
                 (i < 2) ? w32[9] + (i+1)*DENC : nullptr, (i < 2) ? 1 : 0);

    // ---- routing (f32) ----
    k_gemm2<<<dim3(4, BL/64), 256, 0, stream>>>(X, wq, wk, Qr, Kr, DENC);
    k_router<<<BL, 64, 0, stream>>>(Qr, Kr, P, BH, ACC);
    k_seq<<<B_, 64, 0, stream>>>(BH, P, CIDX, SRC, COUNTS, ACC);
    k_scatter2<<<BL, 128, 0, stream>>>(X, P, SRC, COUNTS, COMP16, PCOMP);

    // ---- main stack on compressed ----
    gfl(128, 256, COMP16, w16[4], nullptr, Z, LN16, w32[16], w32[17], 1, 0);   // proj_up + LN1(main0)
    for (int i = 0; i < 6; i++)
        block_main(Z, w16[18] + (size_t)i*3*DMAIN*DMAIN, w16[19] + (size_t)i*DMAIN*DMAIN,
                   w32[20] + i*DMAIN, w32[21] + i*DMAIN,
                   w16[22] + (size_t)i*2*DMAIN*DMAIN, w16[23] + (size_t)i*2*DMAIN*DMAIN,
                   (i < 5) ? w32[16] + (i+1)*DMAIN : nullptr,
                   (i < 5) ? w32[17] + (i+1)*DMAIN : nullptr, (i < 5) ? 1 : 0);
    k_lngemm<256><<<dim3(2, BL/64), 256, 0, stream>>>(Z, w16[5], nullptr, nullptr, 0,
                                                      ZDN, nullptr, FLAG, DENC, 0);   // proj_dn

    // ---- EMA + dechunk combine + LN1(dec0) ----
    k_ema2<<<256, 256, 0, stream>>>(ZDN, PCOMP, ZBAR);
    k_combine_ln<<<BL/4, 256, 0, stream>>>(X, ZBAR, CIDX, w32[24], w32[25], LN16);

    // ---- decoder (final layer fuses the output norm) ----
    for (int i = 0; i < 3; i++)
        block128(X, w16[26] + (size_t)i*3*DENC*DENC, w16[27] + (size_t)i*DENC*DENC,
                 w32[28] + i*DENC, w32[29] + i*DENC,
                 w16[30] + (size_t)i*2*DENC*DENC, w16[31] + (size_t)i*2*DENC*DENC,
                 (i < 2) ? w32[24] + (i+1)*DENC : norm_w,
                 (i < 2) ? w32[25] + (i+1)*DENC : norm_b, 1);

    // ---- tied head (LN16 already = final norm) + loss ----
    hgemm(128, LN16, w16[1], nullptr, nullptr, nullptr, d_out, VOCAB, 3,
          nullptr, nullptr, nullptr, 0, 0);
    k_loss<<<1,1,0,stream>>>(ACC, d_out, FLAG);
}